// Round 9
// baseline (633.156 us; speedup 1.0000x reference)
//
#include <hip/hip_runtime.h>
#include <hip/hip_fp16.h>

// =====================================================================
// GCN pipeline on MI355X, round 15:
//  - base = round-14 (632.5us verified).
//  - NEW: launch-graph re-plumbing only (no math changes).
//    stageA split: gcn_prep = transpose+folds+packs (976 blocks, fast);
//    the 8-block bitonic sort moves into gcn_sort_hc, fused with
//    hc<256> (512 tiles, 4 per 1024-thread block, 135KB LDS). The sort
//    (~70us, 8 CUs) previously overlapped only the cheap packs while
//    stageB/stageC/hc<256> (sort-independent) ran serially after it;
//    now hc<256> hides under the sort.
//  - order: minmax,keys,prep,stageB,stageC,sort_hc, then layers as before.
// =====================================================================

typedef _Float16 half8v  __attribute__((ext_vector_type(8)));
typedef _Float16 half4v  __attribute__((ext_vector_type(4)));
typedef float    float4v __attribute__((ext_vector_type(4)));
typedef float    floatx2 __attribute__((ext_vector_type(2)));

union H4 { half4v v; __half2 h[2]; };
union F2H { floatx2 f; __half2 h[2]; };

// ---------------- workspace layout (bytes) ----------------
constexpr size_t OFF_A1_1   = 0;
constexpr size_t OFF_A2_1   = 2048;
constexpr size_t OFF_A1_2   = 4096;
constexpr size_t OFF_A2_2   = 8192;
constexpr size_t OFF_A1_3   = 12288;
constexpr size_t OFF_A2_3   = 14336;
constexpr size_t OFF_MM     = 16384;                        // 12 floats
constexpr size_t OFF_KEYS   = OFF_MM + 256;
constexpr size_t OFF_INDS   = OFF_KEYS + 8ull*4096*8;
constexpr size_t OFF_PK6_1  = OFF_INDS + 8ull*4096*10*4;    // 1 MB
constexpr size_t OFF_PK6_2  = OFF_PK6_1 + 512ull*1024*2;
constexpr size_t OFF_PK7_1  = OFF_PK6_2 + 512ull*1024*2;
constexpr size_t OFF_PK7_2  = OFF_PK7_1 + 256ull*512*2;
constexpr size_t OFF_WFOLD1 = OFF_PK7_2 + 512ull*512*2;
constexpr size_t OFF_WFOLD2 = OFF_WFOLD1 + 512ull*256*4;
constexpr size_t OFF_WCOMB1 = OFF_WFOLD2 + 512ull*256*4;
constexpr size_t OFF_WCOMB2 = OFF_WCOMB1 + 256ull*256*4;
constexpr size_t OFF_PC1    = OFF_WCOMB2 + 512ull*256*4;
constexpr size_t OFF_PC2    = OFF_PC1 + 256ull*256*2;
constexpr size_t OFF_BC1    = OFF_PC2 + 512ull*256*2;
constexpr size_t OFF_BC2    = OFF_BC1 + 1024;
constexpr size_t OFF_FEATST = OFF_BC2 + 2048;               // (B,N,256) fp16
constexpr size_t OFF_F1T    = OFF_FEATST + 2ull*4096*256*2; // (B,N,256) fp16
constexpr size_t OFF_F2T    = OFF_F1T   + 2ull*4096*256*2;  // (B,N,512) fp16
constexpr size_t OFF_HMAX1  = OFF_F2T   + 2ull*4096*512*2;  // (B,N,256) fp32
constexpr size_t OFF_HMAX2  = OFF_HMAX1 + 2ull*4096*256*4;  // (B,N,512) fp32
constexpr size_t OFF_HC1    = OFF_HMAX2 + 2ull*4096*512*4;  // fp16 (B*N,256)
constexpr size_t OFF_HC2    = OFF_HC1   + 8192ull*256*2;    // fp16 (B*N,512)
constexpr size_t OFF_PF3    = OFF_HC2   + 8192ull*512*2;    // packed Wc3
constexpr size_t WS_NEED    = OFF_PF3   + 256ull*1024*2;
constexpr size_t OFF_H3     = OFF_HMAX1;   // hmax1 dead after norm16-L1

// ---------------- helpers ----------------
__device__ __forceinline__ int gcn_quant1(float c, float cmin, float scale) {
  float q = floorf(__fmul_rn(__fsub_rn(c, cmin), scale));
  q = fminf(fmaxf(q, 0.0f), 1023.0f);
  return (int)q;
}

__device__ __forceinline__ unsigned int gcn_morton3(int x, int y, int z) {
  unsigned int key = 0u;
#pragma unroll
  for (int b = 0; b < 10; ++b) {
    key |= ((unsigned)((x >> b) & 1)) << (3 * b + 2);
    key |= ((unsigned)((y >> b) & 1)) << (3 * b + 1);
    key |= ((unsigned)((z >> b) & 1)) << (3 * b + 0);
  }
  return key;
}

__device__ __forceinline__ unsigned int gcn_hilbert3(int x, int y, int z) {
  int X0 = x, X1 = y, X2 = z;
  for (int Q = 512; Q > 1; Q >>= 1) {
    int P = Q - 1;
    if (X0 & Q) X0 ^= P;
    {
      int t = (X0 ^ X1) & P;
      if (X1 & Q) { X0 ^= P; } else { X0 ^= t; X1 ^= t; }
    }
    {
      int t = (X0 ^ X2) & P;
      if (X2 & Q) { X0 ^= P; } else { X0 ^= t; X2 ^= t; }
    }
  }
  X1 ^= X0;
  X2 ^= X1;
  int t = 0;
  for (int Q = 512; Q > 1; Q >>= 1)
    if (X2 & Q) t ^= (Q - 1);
  X0 ^= t; X1 ^= t; X2 ^= t;
  unsigned int key = 0u;
#pragma unroll
  for (int b = 9; b >= 0; --b) {
    key = (key << 1) | (unsigned)((X0 >> b) & 1);
    key = (key << 1) | (unsigned)((X1 >> b) & 1);
    key = (key << 1) | (unsigned)((X2 >> b) & 1);
  }
  return key;
}

// ---------------- device bodies for fused prep stages ----------------
__device__ void dev_foldF(const float* __restrict__ W, float* __restrict__ Wf, int i) {
  int o = i >> 8, c = i & 255;
  float4 w = ((const float4*)W)[(size_t)o * 512 + c];
  Wf[i] = w.x + w.y + w.z + w.w;
}

__device__ void dev_pack6(const float* __restrict__ W, _Float16* __restrict__ P, int i) {
  int lane = i & 63, ks = (i >> 6) & 31, nt = i >> 11;
  int tl = lane & 15, q = lane >> 4;
  int o = nt * 16 + tl;
  _Float16 tmp[8];
#pragma unroll
  for (int j = 0; j < 8; ++j) {
    int k = ks * 32 + q * 8 + j;
    int hp = k >> 9, r = k & 511, m = r >> 7, cl = r & 127;
    int col = 1024 + 4 * (128 * hp + cl) + m;
    tmp[j] = (_Float16)W[(size_t)o * 2048 + col];
  }
  *(half8v*)(P + (size_t)i * 8) = *(half8v*)tmp;
}

__device__ void dev_pack7(const float* __restrict__ W, _Float16* __restrict__ P, int i) {
  int lane = i & 63, ks = (i >> 6) & 15, nt = i >> 10;
  int tl = lane & 15, q = lane >> 4;
  int o2 = nt * 16 + tl;
  int c2 = ks * 32 + q * 8;
  _Float16 tmp[8];
#pragma unroll
  for (int j = 0; j < 8; ++j)
    tmp[j] = (_Float16)W[(size_t)o2 * 512 + c2 + j];
  *(half8v*)(P + (size_t)i * 8) = *(half8v*)tmp;
}

__device__ void dev_packF(const float* __restrict__ W, _Float16* __restrict__ P, int i) {
  int lane = i & 63, ksg = (i >> 6) & 31, nt = i >> 11;
  int tl = lane & 15, q = lane >> 4;
  int o = nt * 16 + tl;
  _Float16 tmp[8];
#pragma unroll
  for (int j = 0; j < 8; ++j)
    tmp[j] = (_Float16)W[(size_t)o * 1024 + ksg * 32 + q * 8 + j];
  *(half8v*)(P + (size_t)i * 8) = *(half8v*)tmp;
}

__device__ void dev_sort(const unsigned long long* __restrict__ keys,
                         int* __restrict__ inds, int g, int tid,
                         unsigned long long* a) {
  for (int i = tid; i < 4096; i += 1024) a[i] = keys[(size_t)g * 4096 + i];
  __syncthreads();
  for (int k = 2; k <= 4096; k <<= 1) {
    for (int j = k >> 1; j > 0; j >>= 1) {
      for (int t = tid; t < 2048; t += 1024) {
        int i = 2 * t - (t & (j - 1));
        int p = i + j;
        bool up = (i & k) == 0;
        unsigned long long x = a[i], y = a[p];
        if ((x > y) == up) { a[i] = y; a[p] = x; }
      }
      __syncthreads();
    }
  }
  for (int i = tid; i < 4096; i += 1024) {
    int start = i - 5; if (start < 0) start = 0;
    int endm1 = i + 5; if (endm1 > 4095) endm1 = 4095;
#pragma unroll
    for (int kk = 0; kk < 10; ++kk) {
      int pos = start + kk; if (pos > endm1) pos = endm1;
      inds[((size_t)g * 4096 + i) * 10 + kk] = (int)(a[pos] & 0xFFFULL);
    }
  }
}

__device__ void dev_transpose(const float* __restrict__ feats, __half* __restrict__ fT,
                              int vblk, int t256, float* tt) {   // tt: 32*33 floats
  int cb = vblk & 7, nb = (vblk >> 3) & 127, b = vblk >> 10;
  int tx = t256 & 31, ty = t256 >> 5;
#pragma unroll
  for (int i = 0; i < 4; ++i) {
    int c = cb * 32 + ty + i * 8;
    tt[(ty + i * 8) * 33 + tx] = feats[((size_t)(b * 256 + c) << 12) + nb * 32 + tx];
  }
  __syncthreads();
  if (tx < 16) {
#pragma unroll
    for (int i = 0; i < 4; ++i) {
      int nl = ty + i * 8;
      int n = nb * 32 + nl;
      __half2 hv = __floats2half2_rn(tt[(2 * tx) * 33 + nl], tt[(2 * tx + 1) * 33 + nl]);
      *(__half2*)(fT + ((size_t)((b << 12) + n)) * 256 + cb * 32 + 2 * tx) = hv;
    }
  }
}

// hc<256> tile body (256-thread sub-tile; As = 33792 B per sub-tile)
__device__ void dev_hc256(const __half* __restrict__ src,
                          const _Float16* __restrict__ PC,
                          const float* __restrict__ bc,
                          __half* __restrict__ out, int tile, int tid,
                          _Float16* As) {
  int nb = tile & 3, mb = tile >> 2;
  const __half2* s2 = (const __half2*)(src + (size_t)mb * 64 * 256);
  for (int idx = tid; idx < 64 * 128; idx += 256) {
    int row = idx >> 7, cp = idx & 127;
    __half2 v = s2[row * 128 + cp];
    *(__half2*)((char*)As + row * 528 + cp * 4) = v;
  }
  __syncthreads();
  int lane = tid & 63, w = tid >> 6, tl = lane & 15, q = lane >> 4;
  float4v acc[4];
#pragma unroll
  for (int t = 0; t < 4; ++t) acc[t] = (float4v){0.f, 0.f, 0.f, 0.f};
  const half8v* pc = (const half8v*)PC;
#pragma unroll
  for (int ks = 0; ks < 8; ++ks) {
    half8v a = *(const half8v*)((const char*)As + (w * 16 + tl) * 528 + ks * 64 + q * 16);
#pragma unroll
    for (int t = 0; t < 4; ++t) {
      half8v bf = pc[(size_t)(((nb * 4 + t) * 8 + ks)) * 64 + lane];
      acc[t] = __builtin_amdgcn_mfma_f32_16x16x32_f16(a, bf, acc[t], 0, 0, 0);
    }
  }
#pragma unroll
  for (int t = 0; t < 4; ++t) {
    int o = (nb * 4 + t) * 16 + tl;
    float bb = bc[o];
#pragma unroll
    for (int r = 0; r < 4; ++r) {
      int row = mb * 64 + w * 16 + q * 4 + r;
      out[(size_t)row * 256 + o] = __float2half(acc[t][r] + bb);
    }
  }
}

// ---------------- prep: transpose + folds + packs (no sort) ----------------
__global__ __launch_bounds__(1024) void gcn_prep(
    const float* __restrict__ feats, __half* __restrict__ fT,
    const float* __restrict__ W_lin1, const float* __restrict__ W_lin2,
    const float* __restrict__ W_conv1, const float* __restrict__ W_conv2,
    const float* __restrict__ W_conv3,
    float* __restrict__ WFOLD1, float* __restrict__ WFOLD2,
    _Float16* __restrict__ PK61, _Float16* __restrict__ PK62,
    _Float16* __restrict__ PK71, _Float16* __restrict__ PK72,
    _Float16* __restrict__ PF3) {
  __shared__ __align__(16) char smA[32768];
  int blk = blockIdx.x, tid = threadIdx.x;
  if (blk < 512) {
    float* tt = (float*)smA + (tid >> 8) * (32 * 33);
    dev_transpose(feats, fT, blk * 4 + (tid >> 8), tid & 255, tt);
    return;
  }
  blk -= 512;
  if (blk < 128) { dev_foldF(W_lin1, WFOLD1, blk * 1024 + tid); return; }
  blk -= 128;
  if (blk < 128) { dev_foldF(W_lin2, WFOLD2, blk * 1024 + tid); return; }
  blk -= 128;
  if (blk < 64)  { dev_pack6(W_lin1, PK61, blk * 1024 + tid); return; }
  blk -= 64;
  if (blk < 64)  { dev_pack6(W_lin2, PK62, blk * 1024 + tid); return; }
  blk -= 64;
  if (blk < 16)  { dev_pack7(W_conv1, PK71, blk * 1024 + tid); return; }
  blk -= 16;
  if (blk < 32)  { dev_pack7(W_conv2, PK72, blk * 1024 + tid); return; }
  blk -= 32;
  dev_packF(W_conv3, PF3, blk * 1024 + tid);
}
constexpr int PREP_BLOCKS = 512 + 128 + 128 + 64 + 64 + 16 + 32 + 32;  // 976

// ---------------- fused sort + hc<256>: sort (8 blocks) || hc (128 blocks x4) ----------------
__global__ __launch_bounds__(1024) void gcn_sort_hc(
    const unsigned long long* __restrict__ keys, int* __restrict__ inds,
    const __half* __restrict__ src, const _Float16* __restrict__ PC,
    const float* __restrict__ bc, __half* __restrict__ out) {
  __shared__ __align__(16) char sm[135168];
  int blk = blockIdx.x, tid = threadIdx.x;
  if (blk < 8) { dev_sort(keys, inds, blk, tid, (unsigned long long*)sm); return; }
  int tile = (blk - 8) * 4 + (tid >> 8);
  dev_hc256(src, PC, bc, out, tile, tid & 255,
            (_Float16*)(sm + (size_t)(tid >> 8) * 33792));
}
constexpr int SORTHC_BLOCKS = 8 + 128;

// ---------------- stage B: wcomb (both layers, one launch) ----------------
__device__ void dev_wcomb(const float* __restrict__ Wc, const float* __restrict__ blin,
                          const float* __restrict__ WfoldF, float* __restrict__ Wcomb,
                          float* __restrict__ bc, int o2, float* wrow) {
  int tid = threadIdx.x;
  wrow[tid] = Wc[(size_t)o2 * 512 + tid];
  wrow[tid + 256] = Wc[(size_t)o2 * 512 + tid + 256];
  __syncthreads();
  float acc = 0.f;
  for (int o = 0; o < 512; ++o)
    acc = fmaf(wrow[o], WfoldF[(size_t)o * 256 + tid], acc);
  Wcomb[(size_t)o2 * 256 + tid] = acc;
  if (tid == 0) {
    float s = 0.f;
    for (int o = 0; o < 512; ++o) s += wrow[o] * blin[o];
    bc[o2] = s;
  }
}

__global__ __launch_bounds__(256) void gcn_stageB(
    const float* __restrict__ Wc1, const float* __restrict__ b1,
    const float* __restrict__ Wc2, const float* __restrict__ b2,
    const float* __restrict__ WF1, const float* __restrict__ WF2,
    float* __restrict__ WCOMB1, float* __restrict__ BC1,
    float* __restrict__ WCOMB2, float* __restrict__ BC2) {
  __shared__ float wrow[512];
  int blk = blockIdx.x;
  if (blk < 256) dev_wcomb(Wc1, b1, WF1, WCOMB1, BC1, blk, wrow);
  else           dev_wcomb(Wc2, b2, WF2, WCOMB2, BC2, blk - 256, wrow);
}

// ---------------- stage C: packC (both layers) ----------------
__device__ void dev_packC(const float* __restrict__ Wcomb, _Float16* __restrict__ P, int i) {
  int lane = i & 63, ks = (i >> 6) & 7, nt = i >> 9;
  int tl = lane & 15, q = lane >> 4;
  int n = nt * 16 + tl;
  _Float16 tmp[8];
#pragma unroll
  for (int j = 0; j < 8; ++j)
    tmp[j] = (_Float16)Wcomb[(size_t)n * 256 + ks * 32 + q * 8 + j];
  *(half8v*)(P + (size_t)i * 8) = *(half8v*)tmp;
}

__global__ __launch_bounds__(256) void gcn_stageC(
    const float* __restrict__ WCOMB1, _Float16* __restrict__ PC1,
    const float* __restrict__ WCOMB2, _Float16* __restrict__ PC2) {
  int blk = blockIdx.x;
  if (blk < 32) dev_packC(WCOMB1, PC1, blk * 256 + threadIdx.x);
  else          dev_packC(WCOMB2, PC2, (blk - 32) * 256 + threadIdx.x);
}

// ---------------- hc precompute (layer 2 only) ----------------
template <int O2>
__global__ __launch_bounds__(256) void gcn_hc(const __half* __restrict__ src,
                                              const _Float16* __restrict__ PC,
                                              const float* __restrict__ bc,
                                              __half* __restrict__ out) {
  constexpr int NB = O2 / 64;
  __shared__ __align__(16) _Float16 As[64 * 264];
  int nb = blockIdx.x % NB, mb = blockIdx.x / NB;
  int tid = threadIdx.x;
  const __half2* s2 = (const __half2*)(src + (size_t)mb * 64 * 256);
  for (int idx = tid; idx < 64 * 128; idx += 256) {
    int row = idx >> 7, cp = idx & 127;
    __half2 v = s2[row * 128 + cp];
    *(__half2*)((char*)As + row * 528 + cp * 4) = v;
  }
  __syncthreads();
  int lane = tid & 63, w = tid >> 6, tl = lane & 15, q = lane >> 4;
  float4v acc[4];
#pragma unroll
  for (int t = 0; t < 4; ++t) acc[t] = (float4v){0.f, 0.f, 0.f, 0.f};
  const half8v* pc = (const half8v*)PC;
#pragma unroll
  for (int ks = 0; ks < 8; ++ks) {
    half8v a = *(const half8v*)((const char*)As + (w * 16 + tl) * 528 + ks * 64 + q * 16);
#pragma unroll
    for (int t = 0; t < 4; ++t) {
      half8v bf = pc[(size_t)(((nb * 4 + t) * 8 + ks)) * 64 + lane];
      acc[t] = __builtin_amdgcn_mfma_f32_16x16x32_f16(a, bf, acc[t], 0, 0, 0);
    }
  }
#pragma unroll
  for (int t = 0; t < 4; ++t) {
    int o = (nb * 4 + t) * 16 + tl;
    float bb = bc[o];
#pragma unroll
    for (int r = 0; r < 4; ++r) {
      int row = mb * 64 + w * 16 + q * 4 + r;
      out[(size_t)row * O2 + o] = __float2half(acc[t][r] + bb);
    }
  }
}

// ---------------- quantize prep ----------------
__global__ void gcn_minmax(const float* __restrict__ coords, float* __restrict__ mm) {
  __shared__ float slo[256], shi[256];
  int d = blockIdx.x, tid = threadIdx.x;
  float lo = 1e30f, hi = -1e30f;
  for (int i = tid; i < 4096; i += 256) {
    float v = coords[(size_t)d * 4096 + i];
    lo = fminf(lo, v);
    hi = fmaxf(hi, v);
  }
  slo[tid] = lo; shi[tid] = hi;
  __syncthreads();
  for (int s = 128; s > 0; s >>= 1) {
    if (tid < s) {
      slo[tid] = fminf(slo[tid], slo[tid + s]);
      shi[tid] = fmaxf(shi[tid], shi[tid + s]);
    }
    __syncthreads();
  }
  if (tid == 0) {
    mm[d] = slo[0];
    mm[6 + d] = 1023.0f / ((shi[0] - slo[0]) + 1e-6f);
  }
}

__global__ void gcn_keys(const float* __restrict__ coords, const float* __restrict__ mm,
                         unsigned long long* __restrict__ keys) {
  int idx = blockIdx.x * 256 + threadIdx.x;
  int b = idx >> 12, n = idx & 4095;
  const float* cb = coords + (size_t)b * 3 * 4096;
  int q0 = gcn_quant1(cb[n],        mm[b * 3 + 0], mm[6 + b * 3 + 0]);
  int q1 = gcn_quant1(cb[4096 + n], mm[b * 3 + 1], mm[6 + b * 3 + 1]);
  int q2 = gcn_quant1(cb[8192 + n], mm[b * 3 + 2], mm[6 + b * 3 + 2]);
  unsigned long long nn = (unsigned long long)(unsigned)n;
  size_t base = ((size_t)b * 4) * 4096 + n;
  keys[base]         = ((unsigned long long)gcn_morton3(q0, q1, q2) << 12) | nn;
  keys[base + 4096]  = ((unsigned long long)gcn_morton3(q1, q0, q2) << 12) | nn;
  keys[base + 8192]  = ((unsigned long long)gcn_hilbert3(q0, q1, q2) << 12) | nn;
  keys[base + 12288] = ((unsigned long long)gcn_hilbert3(q1, q0, q2) << 12) | nn;
}

// ---------------- fused 4-window MFMA kernel, joint P6/P7 ----------------
constexpr int ROWB   = 1040;
constexpr int SM_SC  = 49920;
constexpr int SM_GRP = 53120;

__device__ __forceinline__ int& idx_at(char* smem, int j) {
  return ((int*)(smem + (j >> 2) * ROWB + 1024))[j & 3];
}

template <int O2>
__global__ __launch_bounds__(1024, 4) void gcn_window(
    const __half* __restrict__ fT, const int* __restrict__ inds,
    const _Float16* __restrict__ PK6, const _Float16* __restrict__ PK7,
    const __half* __restrict__ hc,
    float* __restrict__ hmax, float* __restrict__ A1, float* __restrict__ A2,
    int p0, int p1, int p2, int p3) {
  __shared__ __align__(16) char smem_all[2 * SM_GRP];

  const int tid  = threadIdx.x;
  const int G    = tid >> 9;          // slab group for P1/P23/P4
  const int tid8 = tid & 511;
  const int lane = tid & 63;
  const int w8   = tid8 >> 6;         // group-local wave 0..7
  const int w16  = tid >> 6;          // block wave 0..15 (joint phases)
  const int tl = lane & 15, q = lane >> 4;
  // XCD-aware swizzle: 1024 blocks, 8 XCDs, 128 consecutive per XCD
  const int swz = (blockIdx.x & 7) * 128 + (blockIdx.x >> 3);
  const int b   = swz >> 9;
  const int grp = swz & 511;
  const int n0  = grp * 8 + G * 4;
  char* sm  = smem_all + G * SM_GRP;  // own slab
  char* smA_ = smem_all;
  char* smB_ = smem_all + SM_GRP;
  __half2* sch = (__half2*)(sm + SM_SC);
  const __half* fTb = fT + ((size_t)(b << 12)) * 256;

  // stage window indices into row pads (both groups)
  if (tid8 < 160) {
    int g = tid8 / 40, rem = tid8 % 40, m = rem / 10, kk = rem % 10;
    int meth = (m == 0) ? p0 : (m == 1) ? p1 : (m == 2) ? p2 : p3;
    idx_at(sm, tid8) = inds[((size_t)((b * 4 + meth) << 12) + n0 + g) * 10 + kk];
  }

  // joint accumulators: [fragment mt + 3*slab][col-tile t], 48 VGPRs
  float4v acc6[6][2];
#pragma unroll
  for (int f = 0; f < 6; ++f)
#pragma unroll
    for (int t = 0; t < 2; ++t) acc6[f][t] = (float4v){0.f, 0.f, 0.f, 0.f};

  const half8v* pk6 = (const half8v*)PK6;
  const half8v* pk7 = (const half8v*)PK7;

  // ---- P1: gather head-pair slab (per group); half4 per lane ----
  auto P1 = [&](int hp) {
    const int l32 = lane & 31;
    const int kkh = lane >> 5;
    const int g = w8 >> 1;
    const half4v cv =
        *(const half4v*)(fTb + (size_t)(n0 + g) * 256 + hp * 128 + 4 * l32);
#pragma unroll
    for (int s = 0; s < 2; ++s) {
      const int m = (w8 * 2 + s) & 3;
      const int jb = (g * 4 + m) * 10;
#pragma unroll
      for (int kk2 = 0; kk2 < 10; kk2 += 2) {
        int kk = kk2 + kkh;
        int id = idx_at(sm, jb + kk);
        half4v v = *(const half4v*)(fTb + (size_t)id * 256 + hp * 128 + 4 * l32);
        *(half4v*)(sm + (g * 10 + kk) * ROWB + m * 256 + 8 * l32) = v - cv;
      }
    }
  };

  // ---- P2+P3: wave = (window g2, head hh); scores + in-wave softmax ----
  auto P23 = [&](int hp) {
    (void)hp;
    int g2 = w8 >> 1, hh = w8 & 1;
    float4v as = {0.f, 0.f, 0.f, 0.f};
    const char* rowbase = sm + (g2 * 10 + tl) * ROWB + hh * 128;
#pragma unroll
    for (int m4 = 0; m4 < 4; ++m4) {
      half8v a0 = *(const half8v*)(rowbase + m4 * 256 + q * 16);
      half8v a1 = *(const half8v*)(rowbase + m4 * 256 + 64 + q * 16);
      as = __builtin_amdgcn_mfma_f32_16x16x32_f16(a0, a0, as, 0, 0, 0);
      as = __builtin_amdgcn_mfma_f32_16x16x32_f16(a1, a1, as, 0, 0, 0);
    }
    bool vt = (tl < 10);
    __half2* scb = sch + (g2 * 2 + hh) * 100;
#pragma unroll
    for (int r = 0; r < 4; ++r) {
      float v = vt ? as[r] * 0.0625f : -1e30f;
      float m = v;
      m = fmaxf(m, __shfl_xor(m, 1));
      m = fmaxf(m, __shfl_xor(m, 2));
      m = fmaxf(m, __shfl_xor(m, 4));
      m = fmaxf(m, __shfl_xor(m, 8));
      float e = vt ? __expf(v - m) : 0.f;
      float su = e;
      su += __shfl_xor(su, 1);
      su += __shfl_xor(su, 2);
      su += __shfl_xor(su, 4);
      su += __shfl_xor(su, 8);
      float ar = e / su;
      int row = q * 4 + r;
      if (row < 10 && vt) scb[row * 10 + tl] = __floats2half2_rn(ar, ar);
    }
  };

  // ---- P4: out = attn @ x_diff via __hfma2 (per group) ----
  auto P4 = [&](int hp) {
    (void)hp;
    const int g4 = tid8 >> 7, c4 = tid8 & 127;
    const floatx2* ar2 = (const floatx2*)(sch + (g4 * 2 + ((c4 >> 4) & 1)) * 100);
    __half2 x0[10], x1[10];
#pragma unroll
    for (int j = 0; j < 10; ++j) {
      H4 u;
      u.v = *(const half4v*)(sm + (g4 * 10 + j) * ROWB + 8 * c4);
      x0[j] = u.h[0];
      x1[j] = u.h[1];
    }
#pragma unroll
    for (int kk = 0; kk < 10; ++kk) {
      __half2 a0 = __floats2half2_rn(0.f, 0.f), a1 = a0;
#pragma unroll
      for (int j = 0; j < 10; j += 2) {
        F2H wv;
        wv.f = ar2[kk * 5 + (j >> 1)];
        a0 = __hfma2(wv.h[0], x0[j], a0);
        a1 = __hfma2(wv.h[0], x1[j], a1);
        a0 = __hfma2(wv.h[1], x0[j + 1], a0);
        a1 = __hfma2(wv.h[1], x1[j + 1], a1);
      }
      H4 o;
      o.h[0] = a0;
      o.h[1] = a1;
      *(half4v*)(sm + (g4 * 10 + kk) * ROWB + 8 * c4) = o.v;
    }
  };

  // ---- P6 joint: each B-fragment feeds 6 A-fragments (both slabs) ----
  auto P6 = [&](int hp) {
    __builtin_amdgcn_s_setprio(1);
#pragma unroll 2
    for (int ks = 0; ks < 16; ++ks) {
      half8v a0 = *(const half8v*)(smA_ + (0  + tl) * ROWB + ks * 64 + q * 16);
      half8v a1 = *(const half8v*)(smA_ + (16 + tl) * ROWB + ks * 64 + q * 16);
      half8v a2 = *(const half8v*)(smA_ + (32 + tl) * ROWB + ks * 64 + q * 16);
      half8v a3 = *(const half8v*)(smB_ + (0  + tl) * ROWB + ks * 64 + q * 16);
      half8v a4 = *(const half8v*)(smB_ + (16 + tl) * ROWB + ks * 64 + q * 16);
      half8v a5 = *(const half8v*)(smB_ + (32 + tl) * ROWB + ks * 64 + q * 16);
#pragma unroll
      for (int t = 0; t < 2; ++t) {
        half8v bf = pk6[(size_t)(((w16 * 2 + t) * 32 + hp * 16 + ks)) * 64 + lane];
        acc6[0][t] = __builtin_amdgcn_mfma_f32_16x16x32_f16(a0, bf, acc6[0][t], 0, 0, 0);
        acc6[1][t] = __builtin_amdgcn_mfma_f32_16x16x32_f16(a1, bf, acc6[1][t], 0, 0, 0);
        acc6[2][t] = __builtin_amdgcn_mfma_f32_16x16x32_f16(a2, bf, acc6[2][t], 0, 0, 0);
        acc6[3][t] = __builtin_amdgcn_mfma_f32_16x16x32_f16(a3, bf, acc6[3][t], 0, 0, 0);
        acc6[4][t] = __builtin_amdgcn_mfma_f32_16x16x32_f16(a4, bf, acc6[4][t], 0, 0, 0);
        acc6[5][t] = __builtin_amdgcn_mfma_f32_16x16x32_f16(a5, bf, acc6[5][t], 0, 0, 0);
      }
    }
    __builtin_amdgcn_s_setprio(0);
  };

  // ---- FU joint: write both slabs (wave's 2 col-tiles each) ----
  auto FU = [&]() {
#pragma unroll
    for (int s = 0; s < 2; ++s) {
      char* ss = (s == 0) ? smA_ : smB_;
#pragma unroll
      for (int mt = 0; mt < 3; ++mt)
#pragma unroll
        for (int t = 0; t < 2; ++t) {
          int o = (w16 * 2 + t) * 16 + tl;
#pragma unroll
          for (int r = 0; r < 4; ++r) {
            int row = 16 * mt + q * 4 + r;
            *(__half*)(ss + row * ROWB + o * 2) = __float2half(acc6[mt + 3 * s][t][r]);
          }
        }
    }
  };

  // ---- P7 joint: h = fused @ Wc^T + hc, max_k + atomic stats ----
  auto P7 = [&]() {
    constexpr int NT2 = O2 / 256;     // col-tiles per wave (16 waves cover O2)
    float4v acc7[6][NT2];
#pragma unroll
    for (int f = 0; f < 6; ++f)
#pragma unroll
      for (int t = 0; t < NT2; ++t) acc7[f][t] = (float4v){0.f, 0.f, 0.f, 0.f};
    __builtin_amdgcn_s_setprio(1);
#pragma unroll 2
    for (int ks = 0; ks < 16; ++ks) {
      half8v a0 = *(const half8v*)(smA_ + (0  + tl) * ROWB + ks * 64 + q * 16);
      half8v a1 = *(const half8v*)(smA_ + (16 + tl) * ROWB + ks * 64 + q * 16);
      half8v a2 = *(const half8v*)(smA_ + (32 + tl) * ROWB + ks * 64 + q * 16);
      half8v a3 = *(const half8v*)(smB_ + (0  + tl) * ROWB + ks * 64 + q * 16);
      half8v a4 = *(const half8v*)(smB_ + (16 + tl) * ROWB + ks * 64 + q * 16);
      half8v a5 = *(const half8v*)(smB_ + (32 + tl) * ROWB + ks * 64 + q * 16);
#pragma unroll
      for (int t = 0; t < NT2; ++t) {
        half8v bf = pk7[(size_t)(((w16 * NT2 + t) * 16 + ks)) * 64 + lane];
        acc7[0][t] = __builtin_amdgcn_mfma_f32_16x16x32_f16(a0, bf, acc7[0][t], 0, 0, 0);
        acc7[1][t] = __builtin_amdgcn_mfma_f32_16x16x32_f16(a1, bf, acc7[1][t], 0, 0, 0);
        acc7[2][t] = __builtin_amdgcn_mfma_f32_16x16x32_f16(a2, bf, acc7[2][t], 0, 0, 0);
        acc7[3][t] = __builtin_amdgcn_mfma_f32_16x16x32_f16(a3, bf, acc7[3][t], 0, 0, 0);
        acc7[4][t] = __builtin_amdgcn_mfma_f32_16x16x32_f16(a4, bf, acc7[4][t], 0, 0, 0);
        acc7[5][t] = __builtin_amdgcn_mfma_f32_16x16x32_f16(a5, bf, acc7[5][t], 0, 0, 0);
      }
    }
    __builtin_amdgcn_s_setprio(0);
#pragma unroll
    for (int s = 0; s < 2; ++s) {
      int n0s = grp * 8 + s * 4;
#pragma unroll
      for (int t = 0; t < NT2; ++t) {
        int o2 = (w16 * NT2 + t) * 16 + tl;
        float hcv[4], mx[4], s1[4], s2[4];
#pragma unroll
        for (int g = 0; g < 4; ++g) {
          hcv[g] = __half2float(hc[((size_t)((b << 12) + n0s + g)) * O2 + o2]);
          mx[g] = -1e30f; s1[g] = 0.f; s2[g] = 0.f;
        }
#pragma unroll
        for (int mt = 0; mt < 3; ++mt)
#pragma unroll
          for (int r = 0; r < 4; ++r) {
            int gr = 16 * mt + 4 * q + r;
#pragma unroll
            for (int g = 0; g < 4; ++g) {
              if (gr >= 10 * g && gr < 10 * g + 10) {
                float v = acc7[mt + 3 * s][t][r] + hcv[g];
                mx[g] = fmaxf(mx[g], v);
                s1[g] += v;
                s2[g] = fmaf(v, v, s2[g]);
              }
            }
          }
#pragma unroll
        for (int g = 0; g < 4; ++g) {
          mx[g] = fmaxf(mx[g], __shfl_xor(mx[g], 16));
          mx[g] = fmaxf(mx[g], __shfl_xor(mx[g], 32));
        }
        float s1t = (s1[0] + s1[1]) + (s1[2] + s1[3]);
        float s2t = (s2[0] + s2[1]) + (s2[2] + s2[3]);
        s1t += __shfl_xor(s1t, 16); s1t += __shfl_xor(s1t, 32);
        s2t += __shfl_xor(s2t, 16); s2t += __shfl_xor(s2t, 32);
        if (q == 0) {
#pragma unroll
          for (int g = 0; g < 4; ++g)
            hmax[((size_t)((b << 12) + n0s + g)) * O2 + o2] = mx[g];
          atomicAdd(&A1[b * O2 + o2], s1t);
          atomicAdd(&A2[b * O2 + o2], s2t);
        }
      }
    }
  };

  // ---- lockstep schedule ----
  __syncthreads();
  P1(0);
  __syncthreads();
  P23(0);
  __syncthreads();
  P4(0);
  __syncthreads();
  P6(0);
  __syncthreads();
  P1(1);
  __syncthreads();
  P23(1);
  __syncthreads();
  P4(1);
  __syncthreads();
  P6(1);
  __syncthreads();
  FU();
  __syncthreads();
  P7();
}

// ---------------- final conv via MFMA (atomic stats) ----------------
__global__ __launch_bounds__(256) void gcn_final_mfma(
    const __half* __restrict__ featsT, const __half* __restrict__ f1T,
    const __half* __restrict__ f2T, const _Float16* __restrict__ PF,
    float* __restrict__ h3, float* __restrict__ A1, float* __restrict__ A2) {
  __shared__ __align__(16) char As[64 * 528];
  const int nb = blockIdx.x & 3, mb = blockIdx.x >> 2;   // mb 0..127
  const int tid = threadIdx.x;
  const int lane = tid & 63, w = tid >> 6, tl = lane & 15, q = lane >> 4;
  const int b = mb >> 6;
  const int nbase = (mb & 63) * 64;
  float4v acc[4];
#pragma unroll
  for (int t = 0; t < 4; ++t) acc[t] = (float4v){0.f, 0.f, 0.f, 0.f};
  const half8v* pf = (const half8v*)PF;
#pragma unroll 1
  for (int kc = 0; kc < 4; ++kc) {
    __syncthreads();
    for (int idx = tid; idx < 64 * 128; idx += 256) {
      int nl = idx >> 7, cp = idx & 127;
      size_t rowg = (size_t)(b << 12) + nbase + nl;
      __half2 v;
      if (kc == 0)      v = *(const __half2*)(featsT + rowg * 256 + cp * 2);
      else if (kc == 1) v = *(const __half2*)(f1T + rowg * 256 + cp * 2);
      else if (kc == 2) v = *(const __half2*)(f2T + rowg * 512 + cp * 2);
      else              v = *(const __half2*)(f2T + rowg * 512 + 256 + cp * 2);
      *(__half2*)(As + nl * 528 + cp * 4) = v;
    }
    __syncthreads();
#pragma unroll
    for (int ks = 0; ks < 8; ++ks) {
      int ksg = kc * 8 + ks;
      half8v a = *(const half8v*)(As + (w * 16 + tl) * 528 + ks * 64 + q * 16);
#pragma unroll
      for (int t = 0; t < 4; ++t) {
        half8v bf = pf[(size_t)(((nb * 4 + t) * 32 + ksg)) * 64 + lane];
        acc[t] = __builtin_amdgcn_mfma_f32_16x16x32_f16(a, bf, acc[t], 0, 0, 0);
      }
    }
  }
#pragma unroll
  for (int t = 0; t < 4; ++t) {
    int o = (nb * 4 + t) * 16 + tl;
    float s1 = 0.f, s2 = 0.f;
#pragma unroll
    for (int r = 0; r < 4; ++r) {
      float v = acc[t][r];
      int n = nbase + w * 16 + q * 4 + r;
      h3[((size_t)(b << 12) + n) * 256 + o] = v;
      s1 += v;
      s2 = fmaf(v, v, s2);
    }
    s1 += __shfl_xor(s1, 16); s1 += __shfl_xor(s1, 32);
    s2 += __shfl_xor(s2, 16); s2 += __shfl_xor(s2, 32);
    if (q == 0) {
      atomicAdd(&A1[b * 256 + o], s1);
      atomicAdd(&A2[b * 256 + o], s2);
    }
  }
}

// ---------------- normalize + lrelu (float4), mu/rs inline ----------------
__global__ void gcn_norm16(const float* __restrict__ src, const float* __restrict__ A1,
                           const float* __restrict__ A2, __half* __restrict__ out,
                           int omask, int bshift, float invNK) {
  int idx4 = blockIdx.x * 256 + threadIdx.x;
  int idx = idx4 * 4;
  int o = idx & omask;
  int b = idx >> bshift;
  int t = b * (omask + 1) + o;
  float4 v = *(const float4*)(src + idx);
  float4 s1 = *(const float4*)(A1 + t);
  float4 s2 = *(const float4*)(A2 + t);
  float sv[4] = {v.x, v.y, v.z, v.w};
  float a1[4] = {s1.x, s1.y, s1.z, s1.w};
  float a2[4] = {s2.x, s2.y, s2.z, s2.w};
  _Float16 h[4];
#pragma unroll
  for (int i = 0; i < 4; ++i) {
    float mu = a1[i] * invNK;
    float var = a2[i] * invNK - mu * mu;
    float rs = __frsqrt_rn(var + 1e-5f);
    float x = (sv[i] - mu) * rs;
    x = x > 0.f ? x : 0.2f * x;
    h[i] = (_Float16)x;
  }
  *(half4v*)(out + idx) = *(half4v*)h;
}

// ---------------- final: transpose-norm h3 -> d_out, mu/rs inline ----------------
__global__ __launch_bounds__(256) void gcn_normT(const float* __restrict__ h3,
                                                 const float* __restrict__ A1,
                                                 const float* __restrict__ A2,
                                                 float* __restrict__ out) {
  __shared__ float tile[64][65];
  int x = blockIdx.x;
  int ob = x & 3, nb = (x >> 2) & 63, b = x >> 8;
  int n0 = nb * 64, o0 = ob * 64;
  for (int idx = threadIdx.x; idx < 4096; idx += 256) {
    int nl = idx >> 6, oc = idx & 63;
    tile[nl][oc] = h3[((size_t)(b << 12) + n0 + nl) * 256 + o0 + oc];
  }
  __syncthreads();
  constexpr float invN = 1.0f / 4096.0f;
  for (int idx = threadIdx.x; idx < 4096; idx += 256) {
    int ol = idx >> 6, nc = idx & 63;
    int t = b * 256 + o0 + ol;
    float mu = A1[t] * invN;
    float var = A2[t] * invN - mu * mu;
    float rs = __frsqrt_rn(var + 1e-5f);
    float v = (tile[nc][ol] - mu) * rs;
    v = v > 0.f ? v : 0.2f * v;
    out[((size_t)(b * 256 + o0 + ol) << 12) + n0 + nc] = v;
  }
}

// ---------------- launch ----------------
extern "C" void kernel_launch(void* const* d_in, const int* in_sizes, int n_in,
                              void* d_out, int out_size, void* d_ws, size_t ws_size,
                              hipStream_t stream) {
  (void)in_sizes; (void)n_in; (void)out_size; (void)ws_size;
  const float* coords  = (const float*)d_in[0];
  const float* feats   = (const float*)d_in[1];
  const float* W_lin1  = (const float*)d_in[2];
  const float* b_lin1  = (const float*)d_in[3];
  const float* W_lin2  = (const float*)d_in[4];
  const float* b_lin2  = (const float*)d_in[5];
  const float* W_conv1 = (const float*)d_in[6];
  const float* W_conv2 = (const float*)d_in[7];
  const float* W_conv3 = (const float*)d_in[8];
  char* ws = (char*)d_ws;

  float* A1_1    = (float*)(ws + OFF_A1_1);
  float* A2_1    = (float*)(ws + OFF_A2_1);
  float* A1_2    = (float*)(ws + OFF_A1_2);
  float* A2_2    = (float*)(ws + OFF_A2_2);
  float* A1_3    = (float*)(ws + OFF_A1_3);
  float* A2_3    = (float*)(ws + OFF_A2_3);
  float* F_MM    = (float*)(ws + OFF_MM);
  unsigned long long* KEYS = (unsigned long long*)(ws + OFF_KEYS);
  int* INDS      = (int*)(ws + OFF_INDS);
  _Float16* PK61 = (_Float16*)(ws + OFF_PK6_1);
  _Float16* PK62 = (_Float16*)(ws + OFF_PK6_2);
  _Float16* PK71 = (_Float16*)(ws + OFF_PK7_1);
  _Float16* PK72 = (_Float16*)(ws + OFF_PK7_2);
  float* WFOLD1  = (float*)(ws + OFF_WFOLD1);
  float* WFOLD2  = (float*)(ws + OFF_WFOLD2);
  float* WCOMB1  = (float*)(ws + OFF_WCOMB1);
  float* WCOMB2  = (float*)(ws + OFF_WCOMB2);
  _Float16* PC1  = (_Float16*)(ws + OFF_PC1);
  _Float16* PC2  = (_Float16*)(ws + OFF_PC2);
  float* BC1     = (float*)(ws + OFF_BC1);
  float* BC2     = (float*)(ws + OFF_BC2);
  __half* FEATST = (__half*)(ws + OFF_FEATST);
  __half* F1T    = (__half*)(ws + OFF_F1T);
  __half* F2T    = (__half*)(ws + OFF_F2T);
  float* HMAX1   = (float*)(ws + OFF_HMAX1);
  float* HMAX2   = (float*)(ws + OFF_HMAX2);
  __half* HC1    = (__half*)(ws + OFF_HC1);
  __half* HC2    = (__half*)(ws + OFF_HC2);
  _Float16* PF3  = (_Float16*)(ws + OFF_PF3);
  float* H3      = (float*)(ws + OFF_H3);

  // zero stat accumulators (16 KB), then prep chain
  hipMemsetAsync(ws, 0, 16384, stream);
  gcn_minmax<<<6, 256, 0, stream>>>(coords, F_MM);
  gcn_keys<<<32, 256, 0, stream>>>(coords, F_MM, KEYS);
  gcn_prep<<<PREP_BLOCKS, 1024, 0, stream>>>(
      feats, FEATST, W_lin1, W_lin2, W_conv1, W_conv2, W_conv3,
      WFOLD1, WFOLD2, PK61, PK62, PK71, PK72, PF3);
  gcn_stageB<<<768, 256, 0, stream>>>(W_conv1, b_lin1, W_conv2, b_lin2,
                                      WFOLD1, WFOLD2, WCOMB1, BC1, WCOMB2, BC2);
  gcn_stageC<<<96, 256, 0, stream>>>(WCOMB1, PC1, WCOMB2, PC2);
  // sort (8 blocks) overlaps hc<256> (128 blocks x 4 tiles)
  gcn_sort_hc<<<SORTHC_BLOCKS, 1024, 0, stream>>>(KEYS, INDS, FEATST, PC1, BC1, HC1);

  // layer 1 (perm1 = [2,0,3,1])
  gcn_window<256><<<1024, 1024, 0, stream>>>(
      FEATST, INDS, PK61, PK71, HC1,
      HMAX1, A1_1, A2_1, 2, 0, 3, 1);
  gcn_norm16<<<2048, 256, 0, stream>>>(HMAX1, A1_1, A2_1, F1T, 255, 20,
                                       1.0f / 40960.0f);

  // layer 2 (perm2 = [1,3,0,2])
  gcn_hc<512><<<1024, 256, 0, stream>>>(F1T, PC2, BC2, HC2);
  gcn_window<512><<<1024, 1024, 0, stream>>>(
      F1T, INDS, PK62, PK72, HC2,
      HMAX2, A1_2, A2_2, 1, 3, 0, 2);
  gcn_norm16<<<4096, 256, 0, stream>>>(HMAX2, A1_2, A2_2, F2T, 511, 21,
                                       1.0f / 40960.0f);

  // final conv (MFMA) + transpose-norm
  gcn_final_mfma<<<512, 256, 0, stream>>>(FEATST, F1T, F2T, PF3, H3, A1_3, A2_3);
  gcn_normT<<<512, 256, 0, stream>>>(H3, A1_3, A2_3, (float*)d_out);
}

// Round 10
// 628.999 us; speedup vs baseline: 1.0066x; 1.0066x over previous
//
#include <hip/hip_runtime.h>
#include <hip/hip_fp16.h>

// =====================================================================
// GCN pipeline on MI355X, round 16:
//  - base = round-15 (633us). Theory: remaining tail ~= 14 kernel-
//    boundary bubbles (~6us each); component sums leave ~85us gap.
//  - Launch-count 14 -> 10, bit-identical math:
//    1) stageC folded into stageB (pack PC from registers; WCOMB dead)
//    2) 16KB memset folded into gcn_keys (blocks 0-15 zero stats)
//    3) layer-1 norm16 fused into gcn_norm_hc512 (inline normalize of
//       HMAX1 slice; nb==0 writes F1T)
//    4) layer-2 norm16 + F2T eliminated: final_mfma normalizes HMAX2
//       inline at kc=2/3 (F2T had no other consumer)
// =====================================================================

typedef _Float16 half8v  __attribute__((ext_vector_type(8)));
typedef _Float16 half4v  __attribute__((ext_vector_type(4)));
typedef float    float4v __attribute__((ext_vector_type(4)));
typedef float    floatx2 __attribute__((ext_vector_type(2)));

union H4 { half4v v; __half2 h[2]; };
union F2H { floatx2 f; __half2 h[2]; };

// ---------------- workspace layout (bytes) ----------------
constexpr size_t OFF_A1_1   = 0;
constexpr size_t OFF_A2_1   = 2048;
constexpr size_t OFF_A1_2   = 4096;
constexpr size_t OFF_A2_2   = 8192;
constexpr size_t OFF_A1_3   = 12288;
constexpr size_t OFF_A2_3   = 14336;
constexpr size_t OFF_MM     = 16384;                        // 12 floats
constexpr size_t OFF_KEYS   = OFF_MM + 256;
constexpr size_t OFF_INDS   = OFF_KEYS + 8ull*4096*8;
constexpr size_t OFF_PK6_1  = OFF_INDS + 8ull*4096*10*4;    // 1 MB
constexpr size_t OFF_PK6_2  = OFF_PK6_1 + 512ull*1024*2;
constexpr size_t OFF_PK7_1  = OFF_PK6_2 + 512ull*1024*2;
constexpr size_t OFF_PK7_2  = OFF_PK7_1 + 256ull*512*2;
constexpr size_t OFF_WFOLD1 = OFF_PK7_2 + 512ull*512*2;
constexpr size_t OFF_WFOLD2 = OFF_WFOLD1 + 512ull*256*4;
constexpr size_t OFF_PC1    = OFF_WFOLD2 + 512ull*256*4;
constexpr size_t OFF_PC2    = OFF_PC1 + 256ull*256*2;
constexpr size_t OFF_BC1    = OFF_PC2 + 512ull*256*2;
constexpr size_t OFF_BC2    = OFF_BC1 + 1024;
constexpr size_t OFF_FEATST = OFF_BC2 + 2048;               // (B,N,256) fp16
constexpr size_t OFF_F1T    = OFF_FEATST + 2ull*4096*256*2; // (B,N,256) fp16
constexpr size_t OFF_HMAX1  = OFF_F1T   + 2ull*4096*256*2;  // (B,N,256) fp32
constexpr size_t OFF_HMAX2  = OFF_HMAX1 + 2ull*4096*256*4;  // (B,N,512) fp32
constexpr size_t OFF_HC1    = OFF_HMAX2 + 2ull*4096*512*4;  // fp16 (B*N,256)
constexpr size_t OFF_HC2    = OFF_HC1   + 8192ull*256*2;    // fp16 (B*N,512)
constexpr size_t OFF_PF3    = OFF_HC2   + 8192ull*512*2;    // packed Wc3
constexpr size_t WS_NEED    = OFF_PF3   + 256ull*1024*2;
constexpr size_t OFF_H3     = OFF_HMAX1;   // hmax1 dead after norm_hc512

// ---------------- helpers ----------------
__device__ __forceinline__ int gcn_quant1(float c, float cmin, float scale) {
  float q = floorf(__fmul_rn(__fsub_rn(c, cmin), scale));
  q = fminf(fmaxf(q, 0.0f), 1023.0f);
  return (int)q;
}

__device__ __forceinline__ unsigned int gcn_morton3(int x, int y, int z) {
  unsigned int key = 0u;
#pragma unroll
  for (int b = 0; b < 10; ++b) {
    key |= ((unsigned)((x >> b) & 1)) << (3 * b + 2);
    key |= ((unsigned)((y >> b) & 1)) << (3 * b + 1);
    key |= ((unsigned)((z >> b) & 1)) << (3 * b + 0);
  }
  return key;
}

__device__ __forceinline__ unsigned int gcn_hilbert3(int x, int y, int z) {
  int X0 = x, X1 = y, X2 = z;
  for (int Q = 512; Q > 1; Q >>= 1) {
    int P = Q - 1;
    if (X0 & Q) X0 ^= P;
    {
      int t = (X0 ^ X1) & P;
      if (X1 & Q) { X0 ^= P; } else { X0 ^= t; X1 ^= t; }
    }
    {
      int t = (X0 ^ X2) & P;
      if (X2 & Q) { X0 ^= P; } else { X0 ^= t; X2 ^= t; }
    }
  }
  X1 ^= X0;
  X2 ^= X1;
  int t = 0;
  for (int Q = 512; Q > 1; Q >>= 1)
    if (X2 & Q) t ^= (Q - 1);
  X0 ^= t; X1 ^= t; X2 ^= t;
  unsigned int key = 0u;
#pragma unroll
  for (int b = 9; b >= 0; --b) {
    key = (key << 1) | (unsigned)((X0 >> b) & 1);
    key = (key << 1) | (unsigned)((X1 >> b) & 1);
    key = (key << 1) | (unsigned)((X2 >> b) & 1);
  }
  return key;
}

// ---------------- device bodies for fused prep stages ----------------
__device__ void dev_foldF(const float* __restrict__ W, float* __restrict__ Wf, int i) {
  int o = i >> 8, c = i & 255;
  float4 w = ((const float4*)W)[(size_t)o * 512 + c];
  Wf[i] = w.x + w.y + w.z + w.w;
}

__device__ void dev_pack6(const float* __restrict__ W, _Float16* __restrict__ P, int i) {
  int lane = i & 63, ks = (i >> 6) & 31, nt = i >> 11;
  int tl = lane & 15, q = lane >> 4;
  int o = nt * 16 + tl;
  _Float16 tmp[8];
#pragma unroll
  for (int j = 0; j < 8; ++j) {
    int k = ks * 32 + q * 8 + j;
    int hp = k >> 9, r = k & 511, m = r >> 7, cl = r & 127;
    int col = 1024 + 4 * (128 * hp + cl) + m;
    tmp[j] = (_Float16)W[(size_t)o * 2048 + col];
  }
  *(half8v*)(P + (size_t)i * 8) = *(half8v*)tmp;
}

__device__ void dev_pack7(const float* __restrict__ W, _Float16* __restrict__ P, int i) {
  int lane = i & 63, ks = (i >> 6) & 15, nt = i >> 10;
  int tl = lane & 15, q = lane >> 4;
  int o2 = nt * 16 + tl;
  int c2 = ks * 32 + q * 8;
  _Float16 tmp[8];
#pragma unroll
  for (int j = 0; j < 8; ++j)
    tmp[j] = (_Float16)W[(size_t)o2 * 512 + c2 + j];
  *(half8v*)(P + (size_t)i * 8) = *(half8v*)tmp;
}

__device__ void dev_packF(const float* __restrict__ W, _Float16* __restrict__ P, int i) {
  int lane = i & 63, ksg = (i >> 6) & 31, nt = i >> 11;
  int tl = lane & 15, q = lane >> 4;
  int o = nt * 16 + tl;
  _Float16 tmp[8];
#pragma unroll
  for (int j = 0; j < 8; ++j)
    tmp[j] = (_Float16)W[(size_t)o * 1024 + ksg * 32 + q * 8 + j];
  *(half8v*)(P + (size_t)i * 8) = *(half8v*)tmp;
}

__device__ void dev_sort(const unsigned long long* __restrict__ keys,
                         int* __restrict__ inds, int g, int tid,
                         unsigned long long* a) {
  for (int i = tid; i < 4096; i += 1024) a[i] = keys[(size_t)g * 4096 + i];
  __syncthreads();
  for (int k = 2; k <= 4096; k <<= 1) {
    for (int j = k >> 1; j > 0; j >>= 1) {
      for (int t = tid; t < 2048; t += 1024) {
        int i = 2 * t - (t & (j - 1));
        int p = i + j;
        bool up = (i & k) == 0;
        unsigned long long x = a[i], y = a[p];
        if ((x > y) == up) { a[i] = y; a[p] = x; }
      }
      __syncthreads();
    }
  }
  for (int i = tid; i < 4096; i += 1024) {
    int start = i - 5; if (start < 0) start = 0;
    int endm1 = i + 5; if (endm1 > 4095) endm1 = 4095;
#pragma unroll
    for (int kk = 0; kk < 10; ++kk) {
      int pos = start + kk; if (pos > endm1) pos = endm1;
      inds[((size_t)g * 4096 + i) * 10 + kk] = (int)(a[pos] & 0xFFFULL);
    }
  }
}

__device__ void dev_transpose(const float* __restrict__ feats, __half* __restrict__ fT,
                              int vblk, int t256, float* tt) {   // tt: 32*33 floats
  int cb = vblk & 7, nb = (vblk >> 3) & 127, b = vblk >> 10;
  int tx = t256 & 31, ty = t256 >> 5;
#pragma unroll
  for (int i = 0; i < 4; ++i) {
    int c = cb * 32 + ty + i * 8;
    tt[(ty + i * 8) * 33 + tx] = feats[((size_t)(b * 256 + c) << 12) + nb * 32 + tx];
  }
  __syncthreads();
  if (tx < 16) {
#pragma unroll
    for (int i = 0; i < 4; ++i) {
      int nl = ty + i * 8;
      int n = nb * 32 + nl;
      __half2 hv = __floats2half2_rn(tt[(2 * tx) * 33 + nl], tt[(2 * tx + 1) * 33 + nl]);
      *(__half2*)(fT + ((size_t)((b << 12) + n)) * 256 + cb * 32 + 2 * tx) = hv;
    }
  }
}

// hc<256> tile body (256-thread sub-tile; As = 33792 B per sub-tile)
__device__ void dev_hc256(const __half* __restrict__ src,
                          const _Float16* __restrict__ PC,
                          const float* __restrict__ bc,
                          __half* __restrict__ out, int tile, int tid,
                          _Float16* As) {
  int nb = tile & 3, mb = tile >> 2;
  const __half2* s2 = (const __half2*)(src + (size_t)mb * 64 * 256);
  for (int idx = tid; idx < 64 * 128; idx += 256) {
    int row = idx >> 7, cp = idx & 127;
    __half2 v = s2[row * 128 + cp];
    *(__half2*)((char*)As + row * 528 + cp * 4) = v;
  }
  __syncthreads();
  int lane = tid & 63, w = tid >> 6, tl = lane & 15, q = lane >> 4;
  float4v acc[4];
#pragma unroll
  for (int t = 0; t < 4; ++t) acc[t] = (float4v){0.f, 0.f, 0.f, 0.f};
  const half8v* pc = (const half8v*)PC;
#pragma unroll
  for (int ks = 0; ks < 8; ++ks) {
    half8v a = *(const half8v*)((const char*)As + (w * 16 + tl) * 528 + ks * 64 + q * 16);
#pragma unroll
    for (int t = 0; t < 4; ++t) {
      half8v bf = pc[(size_t)(((nb * 4 + t) * 8 + ks)) * 64 + lane];
      acc[t] = __builtin_amdgcn_mfma_f32_16x16x32_f16(a, bf, acc[t], 0, 0, 0);
    }
  }
#pragma unroll
  for (int t = 0; t < 4; ++t) {
    int o = (nb * 4 + t) * 16 + tl;
    float bb = bc[o];
#pragma unroll
    for (int r = 0; r < 4; ++r) {
      int row = mb * 64 + w * 16 + q * 4 + r;
      out[(size_t)row * 256 + o] = __float2half(acc[t][r] + bb);
    }
  }
}

// ---------------- prep: transpose + folds + packs (no sort) ----------------
__global__ __launch_bounds__(1024) void gcn_prep(
    const float* __restrict__ feats, __half* __restrict__ fT,
    const float* __restrict__ W_lin1, const float* __restrict__ W_lin2,
    const float* __restrict__ W_conv1, const float* __restrict__ W_conv2,
    const float* __restrict__ W_conv3,
    float* __restrict__ WFOLD1, float* __restrict__ WFOLD2,
    _Float16* __restrict__ PK61, _Float16* __restrict__ PK62,
    _Float16* __restrict__ PK71, _Float16* __restrict__ PK72,
    _Float16* __restrict__ PF3) {
  __shared__ __align__(16) char smA[32768];
  int blk = blockIdx.x, tid = threadIdx.x;
  if (blk < 512) {
    float* tt = (float*)smA + (tid >> 8) * (32 * 33);
    dev_transpose(feats, fT, blk * 4 + (tid >> 8), tid & 255, tt);
    return;
  }
  blk -= 512;
  if (blk < 128) { dev_foldF(W_lin1, WFOLD1, blk * 1024 + tid); return; }
  blk -= 128;
  if (blk < 128) { dev_foldF(W_lin2, WFOLD2, blk * 1024 + tid); return; }
  blk -= 128;
  if (blk < 64)  { dev_pack6(W_lin1, PK61, blk * 1024 + tid); return; }
  blk -= 64;
  if (blk < 64)  { dev_pack6(W_lin2, PK62, blk * 1024 + tid); return; }
  blk -= 64;
  if (blk < 16)  { dev_pack7(W_conv1, PK71, blk * 1024 + tid); return; }
  blk -= 16;
  if (blk < 32)  { dev_pack7(W_conv2, PK72, blk * 1024 + tid); return; }
  blk -= 32;
  dev_packF(W_conv3, PF3, blk * 1024 + tid);
}
constexpr int PREP_BLOCKS = 512 + 128 + 128 + 64 + 64 + 16 + 32 + 32;  // 976

// ---------------- fused sort + hc<256> ----------------
__global__ __launch_bounds__(1024) void gcn_sort_hc(
    const unsigned long long* __restrict__ keys, int* __restrict__ inds,
    const __half* __restrict__ src, const _Float16* __restrict__ PC,
    const float* __restrict__ bc, __half* __restrict__ out) {
  __shared__ __align__(16) char sm[135168];
  int blk = blockIdx.x, tid = threadIdx.x;
  if (blk < 8) { dev_sort(keys, inds, blk, tid, (unsigned long long*)sm); return; }
  int tile = (blk - 8) * 4 + (tid >> 8);
  dev_hc256(src, PC, bc, out, tile, tid & 255,
            (_Float16*)(sm + (size_t)(tid >> 8) * 33792));
}
constexpr int SORTHC_BLOCKS = 8 + 128;

// ---------------- stage B: wcomb + direct PC pack (stageC folded in) ----------------
__device__ void dev_wcomb_pack(const float* __restrict__ Wc, const float* __restrict__ blin,
                               const float* __restrict__ WfoldF, _Float16* __restrict__ PC,
                               float* __restrict__ bc, int o2, float* wrow) {
  int tid = threadIdx.x;
  wrow[tid] = Wc[(size_t)o2 * 512 + tid];
  wrow[tid + 256] = Wc[(size_t)o2 * 512 + tid + 256];
  __syncthreads();
  float acc = 0.f;
  for (int o = 0; o < 512; ++o)
    acc = fmaf(wrow[o], WfoldF[(size_t)o * 256 + tid], acc);
  // pack directly (inverse of dev_packC index algebra):
  // row n=o2, col c=tid: ks=c>>5, q=(c>>3)&3, j=c&7; nt=n>>4, tl=n&15
  int n = o2, c = tid;
  size_t pidx =
      ((size_t)(n >> 4) * 512 + (size_t)((c >> 5) * 64 + ((c >> 3) & 3) * 16 + (n & 15))) * 8
      + (c & 7);
  PC[pidx] = (_Float16)acc;
  if (tid == 0) {
    float s = 0.f;
    for (int o = 0; o < 512; ++o) s += wrow[o] * blin[o];
    bc[o2] = s;
  }
}

__global__ __launch_bounds__(256) void gcn_stageB(
    const float* __restrict__ Wc1, const float* __restrict__ b1,
    const float* __restrict__ Wc2, const float* __restrict__ b2,
    const float* __restrict__ WF1, const float* __restrict__ WF2,
    _Float16* __restrict__ PC1, float* __restrict__ BC1,
    _Float16* __restrict__ PC2, float* __restrict__ BC2) {
  __shared__ float wrow[512];
  int blk = blockIdx.x;
  if (blk < 256) dev_wcomb_pack(Wc1, b1, WF1, PC1, BC1, blk, wrow);
  else           dev_wcomb_pack(Wc2, b2, WF2, PC2, BC2, blk - 256, wrow);
}

// ---------------- quantize prep ----------------
__global__ void gcn_minmax(const float* __restrict__ coords, float* __restrict__ mm) {
  __shared__ float slo[256], shi[256];
  int d = blockIdx.x, tid = threadIdx.x;
  float lo = 1e30f, hi = -1e30f;
  for (int i = tid; i < 4096; i += 256) {
    float v = coords[(size_t)d * 4096 + i];
    lo = fminf(lo, v);
    hi = fmaxf(hi, v);
  }
  slo[tid] = lo; shi[tid] = hi;
  __syncthreads();
  for (int s = 128; s > 0; s >>= 1) {
    if (tid < s) {
      slo[tid] = fminf(slo[tid], slo[tid + s]);
      shi[tid] = fmaxf(shi[tid], shi[tid + s]);
    }
    __syncthreads();
  }
  if (tid == 0) {
    mm[d] = slo[0];
    mm[6 + d] = 1023.0f / ((shi[0] - slo[0]) + 1e-6f);
  }
}

// keys + zero the 16KB stat accumulators (memset launch folded in)
__global__ void gcn_keys(const float* __restrict__ coords, const float* __restrict__ mm,
                         unsigned long long* __restrict__ keys,
                         float* __restrict__ AZ) {
  if (blockIdx.x < 16) AZ[blockIdx.x * 256 + threadIdx.x] = 0.f;
  int idx = blockIdx.x * 256 + threadIdx.x;
  int b = idx >> 12, n = idx & 4095;
  const float* cb = coords + (size_t)b * 3 * 4096;
  int q0 = gcn_quant1(cb[n],        mm[b * 3 + 0], mm[6 + b * 3 + 0]);
  int q1 = gcn_quant1(cb[4096 + n], mm[b * 3 + 1], mm[6 + b * 3 + 1]);
  int q2 = gcn_quant1(cb[8192 + n], mm[b * 3 + 2], mm[6 + b * 3 + 2]);
  unsigned long long nn = (unsigned long long)(unsigned)n;
  size_t base = ((size_t)b * 4) * 4096 + n;
  keys[base]         = ((unsigned long long)gcn_morton3(q0, q1, q2) << 12) | nn;
  keys[base + 4096]  = ((unsigned long long)gcn_morton3(q1, q0, q2) << 12) | nn;
  keys[base + 8192]  = ((unsigned long long)gcn_hilbert3(q0, q1, q2) << 12) | nn;
  keys[base + 12288] = ((unsigned long long)gcn_hilbert3(q1, q0, q2) << 12) | nn;
}

// ---------------- fused norm(layer1) + hc<512> ----------------
// block (nb 0..7, mb 0..127): normalize HMAX1 rows [mb*64,+64) inline
// (same formula/rounding as old norm16), nb==0 writes F1T, then hc MFMA.
__global__ __launch_bounds__(256) void gcn_norm_hc512(
    const float* __restrict__ hmax1, const float* __restrict__ A1,
    const float* __restrict__ A2, __half* __restrict__ f1T,
    const _Float16* __restrict__ PC, const float* __restrict__ bc,
    __half* __restrict__ out) {
  __shared__ __align__(16) _Float16 As[64 * 264];
  int nb = blockIdx.x & 7, mb = blockIdx.x >> 3;
  int tid = threadIdx.x;
  int bb = mb >> 6;
  constexpr float invNK = 1.0f / 40960.0f;
  const float* src = hmax1 + (size_t)mb * 64 * 256;
  for (int idx = tid; idx < 64 * 128; idx += 256) {
    int row = idx >> 7, cp = idx & 127;
    int c0 = cp * 2;
    float x0 = src[row * 256 + c0];
    float x1 = src[row * 256 + c0 + 1];
    int t0 = bb * 256 + c0;
    float mu0 = A1[t0] * invNK;
    float var0 = A2[t0] * invNK - mu0 * mu0;
    float rs0 = __frsqrt_rn(var0 + 1e-5f);
    float mu1 = A1[t0 + 1] * invNK;
    float var1 = A2[t0 + 1] * invNK - mu1 * mu1;
    float rs1 = __frsqrt_rn(var1 + 1e-5f);
    float y0 = (x0 - mu0) * rs0; y0 = y0 > 0.f ? y0 : 0.2f * y0;
    float y1 = (x1 - mu1) * rs1; y1 = y1 > 0.f ? y1 : 0.2f * y1;
    __half2 hv = __floats2half2_rn(y0, y1);
    *(__half2*)((char*)As + row * 528 + cp * 4) = hv;
    if (nb == 0)
      *(__half2*)(f1T + ((size_t)mb * 64 + row) * 256 + c0) = hv;
  }
  __syncthreads();
  int lane = tid & 63, w = tid >> 6, tl = lane & 15, q = lane >> 4;
  float4v acc[4];
#pragma unroll
  for (int t = 0; t < 4; ++t) acc[t] = (float4v){0.f, 0.f, 0.f, 0.f};
  const half8v* pc = (const half8v*)PC;
#pragma unroll
  for (int ks = 0; ks < 8; ++ks) {
    half8v a = *(const half8v*)((const char*)As + (w * 16 + tl) * 528 + ks * 64 + q * 16);
#pragma unroll
    for (int t = 0; t < 4; ++t) {
      half8v bf = pc[(size_t)(((nb * 4 + t) * 8 + ks)) * 64 + lane];
      acc[t] = __builtin_amdgcn_mfma_f32_16x16x32_f16(a, bf, acc[t], 0, 0, 0);
    }
  }
#pragma unroll
  for (int t = 0; t < 4; ++t) {
    int o = (nb * 4 + t) * 16 + tl;
    float bv = bc[o];
#pragma unroll
    for (int r = 0; r < 4; ++r) {
      int row = mb * 64 + w * 16 + q * 4 + r;
      out[(size_t)row * 512 + o] = __float2half(acc[t][r] + bv);
    }
  }
}

// ---------------- fused 4-window MFMA kernel, joint P6/P7 ----------------
constexpr int ROWB   = 1040;
constexpr int SM_SC  = 49920;
constexpr int SM_GRP = 53120;

__device__ __forceinline__ int& idx_at(char* smem, int j) {
  return ((int*)(smem + (j >> 2) * ROWB + 1024))[j & 3];
}

template <int O2>
__global__ __launch_bounds__(1024, 4) void gcn_window(
    const __half* __restrict__ fT, const int* __restrict__ inds,
    const _Float16* __restrict__ PK6, const _Float16* __restrict__ PK7,
    const __half* __restrict__ hc,
    float* __restrict__ hmax, float* __restrict__ A1, float* __restrict__ A2,
    int p0, int p1, int p2, int p3) {
  __shared__ __align__(16) char smem_all[2 * SM_GRP];

  const int tid  = threadIdx.x;
  const int G    = tid >> 9;
  const int tid8 = tid & 511;
  const int lane = tid & 63;
  const int w8   = tid8 >> 6;
  const int w16  = tid >> 6;
  const int tl = lane & 15, q = lane >> 4;
  const int swz = (blockIdx.x & 7) * 128 + (blockIdx.x >> 3);
  const int b   = swz >> 9;
  const int grp = swz & 511;
  const int n0  = grp * 8 + G * 4;
  char* sm  = smem_all + G * SM_GRP;
  char* smA_ = smem_all;
  char* smB_ = smem_all + SM_GRP;
  __half2* sch = (__half2*)(sm + SM_SC);
  const __half* fTb = fT + ((size_t)(b << 12)) * 256;

  if (tid8 < 160) {
    int g = tid8 / 40, rem = tid8 % 40, m = rem / 10, kk = rem % 10;
    int meth = (m == 0) ? p0 : (m == 1) ? p1 : (m == 2) ? p2 : p3;
    idx_at(sm, tid8) = inds[((size_t)((b * 4 + meth) << 12) + n0 + g) * 10 + kk];
  }

  float4v acc6[6][2];
#pragma unroll
  for (int f = 0; f < 6; ++f)
#pragma unroll
    for (int t = 0; t < 2; ++t) acc6[f][t] = (float4v){0.f, 0.f, 0.f, 0.f};

  const half8v* pk6 = (const half8v*)PK6;
  const half8v* pk7 = (const half8v*)PK7;

  auto P1 = [&](int hp) {
    const int l32 = lane & 31;
    const int kkh = lane >> 5;
    const int g = w8 >> 1;
    const half4v cv =
        *(const half4v*)(fTb + (size_t)(n0 + g) * 256 + hp * 128 + 4 * l32);
#pragma unroll
    for (int s = 0; s < 2; ++s) {
      const int m = (w8 * 2 + s) & 3;
      const int jb = (g * 4 + m) * 10;
#pragma unroll
      for (int kk2 = 0; kk2 < 10; kk2 += 2) {
        int kk = kk2 + kkh;
        int id = idx_at(sm, jb + kk);
        half4v v = *(const half4v*)(fTb + (size_t)id * 256 + hp * 128 + 4 * l32);
        *(half4v*)(sm + (g * 10 + kk) * ROWB + m * 256 + 8 * l32) = v - cv;
      }
    }
  };

  auto P23 = [&](int hp) {
    (void)hp;
    int g2 = w8 >> 1, hh = w8 & 1;
    float4v as = {0.f, 0.f, 0.f, 0.f};
    const char* rowbase = sm + (g2 * 10 + tl) * ROWB + hh * 128;
#pragma unroll
    for (int m4 = 0; m4 < 4; ++m4) {
      half8v a0 = *(const half8v*)(rowbase + m4 * 256 + q * 16);
      half8v a1 = *(const half8v*)(rowbase + m4 * 256 + 64 + q * 16);
      as = __builtin_amdgcn_mfma_f32_16x16x32_f16(a0, a0, as, 0, 0, 0);
      as = __builtin_amdgcn_mfma_f32_16x16x32_f16(a1, a1, as, 0, 0, 0);
    }
    bool vt = (tl < 10);
    __half2* scb = sch + (g2 * 2 + hh) * 100;
#pragma unroll
    for (int r = 0; r < 4; ++r) {
      float v = vt ? as[r] * 0.0625f : -1e30f;
      float m = v;
      m = fmaxf(m, __shfl_xor(m, 1));
      m = fmaxf(m, __shfl_xor(m, 2));
      m = fmaxf(m, __shfl_xor(m, 4));
      m = fmaxf(m, __shfl_xor(m, 8));
      float e = vt ? __expf(v - m) : 0.f;
      float su = e;
      su += __shfl_xor(su, 1);
      su += __shfl_xor(su, 2);
      su += __shfl_xor(su, 4);
      su += __shfl_xor(su, 8);
      float ar = e / su;
      int row = q * 4 + r;
      if (row < 10 && vt) scb[row * 10 + tl] = __floats2half2_rn(ar, ar);
    }
  };

  auto P4 = [&](int hp) {
    (void)hp;
    const int g4 = tid8 >> 7, c4 = tid8 & 127;
    const floatx2* ar2 = (const floatx2*)(sch + (g4 * 2 + ((c4 >> 4) & 1)) * 100);
    __half2 x0[10], x1[10];
#pragma unroll
    for (int j = 0; j < 10; ++j) {
      H4 u;
      u.v = *(const half4v*)(sm + (g4 * 10 + j) * ROWB + 8 * c4);
      x0[j] = u.h[0];
      x1[j] = u.h[1];
    }
#pragma unroll
    for (int kk = 0; kk < 10; ++kk) {
      __half2 a0 = __floats2half2_rn(0.f, 0.f), a1 = a0;
#pragma unroll
      for (int j = 0; j < 10; j += 2) {
        F2H wv;
        wv.f = ar2[kk * 5 + (j >> 1)];
        a0 = __hfma2(wv.h[0], x0[j], a0);
        a1 = __hfma2(wv.h[0], x1[j], a1);
        a0 = __hfma2(wv.h[1], x0[j + 1], a0);
        a1 = __hfma2(wv.h[1], x1[j + 1], a1);
      }
      H4 o;
      o.h[0] = a0;
      o.h[1] = a1;
      *(half4v*)(sm + (g4 * 10 + kk) * ROWB + 8 * c4) = o.v;
    }
  };

  auto P6 = [&](int hp) {
    __builtin_amdgcn_s_setprio(1);
#pragma unroll 2
    for (int ks = 0; ks < 16; ++ks) {
      half8v a0 = *(const half8v*)(smA_ + (0  + tl) * ROWB + ks * 64 + q * 16);
      half8v a1 = *(const half8v*)(smA_ + (16 + tl) * ROWB + ks * 64 + q * 16);
      half8v a2 = *(const half8v*)(smA_ + (32 + tl) * ROWB + ks * 64 + q * 16);
      half8v a3 = *(const half8v*)(smB_ + (0  + tl) * ROWB + ks * 64 + q * 16);
      half8v a4 = *(const half8v*)(smB_ + (16 + tl) * ROWB + ks * 64 + q * 16);
      half8v a5 = *(const half8v*)(smB_ + (32 + tl) * ROWB + ks * 64 + q * 16);
#pragma unroll
      for (int t = 0; t < 2; ++t) {
        half8v bf = pk6[(size_t)(((w16 * 2 + t) * 32 + hp * 16 + ks)) * 64 + lane];
        acc6[0][t] = __builtin_amdgcn_mfma_f32_16x16x32_f16(a0, bf, acc6[0][t], 0, 0, 0);
        acc6[1][t] = __builtin_amdgcn_mfma_f32_16x16x32_f16(a1, bf, acc6[1][t], 0, 0, 0);
        acc6[2][t] = __builtin_amdgcn_mfma_f32_16x16x32_f16(a2, bf, acc6[2][t], 0, 0, 0);
        acc6[3][t] = __builtin_amdgcn_mfma_f32_16x16x32_f16(a3, bf, acc6[3][t], 0, 0, 0);
        acc6[4][t] = __builtin_amdgcn_mfma_f32_16x16x32_f16(a4, bf, acc6[4][t], 0, 0, 0);
        acc6[5][t] = __builtin_amdgcn_mfma_f32_16x16x32_f16(a5, bf, acc6[5][t], 0, 0, 0);
      }
    }
    __builtin_amdgcn_s_setprio(0);
  };

  auto FU = [&]() {
#pragma unroll
    for (int s = 0; s < 2; ++s) {
      char* ss = (s == 0) ? smA_ : smB_;
#pragma unroll
      for (int mt = 0; mt < 3; ++mt)
#pragma unroll
        for (int t = 0; t < 2; ++t) {
          int o = (w16 * 2 + t) * 16 + tl;
#pragma unroll
          for (int r = 0; r < 4; ++r) {
            int row = 16 * mt + q * 4 + r;
            *(__half*)(ss + row * ROWB + o * 2) = __float2half(acc6[mt + 3 * s][t][r]);
          }
        }
    }
  };

  auto P7 = [&]() {
    constexpr int NT2 = O2 / 256;
    float4v acc7[6][NT2];
#pragma unroll
    for (int f = 0; f < 6; ++f)
#pragma unroll
      for (int t = 0; t < NT2; ++t) acc7[f][t] = (float4v){0.f, 0.f, 0.f, 0.f};
    __builtin_amdgcn_s_setprio(1);
#pragma unroll 2
    for (int ks = 0; ks < 16; ++ks) {
      half8v a0 = *(const half8v*)(smA_ + (0  + tl) * ROWB + ks * 64 + q * 16);
      half8v a1 = *(const half8v*)(smA_ + (16 + tl) * ROWB + ks * 64 + q * 16);
      half8v a2 = *(const half8v*)(smA_ + (32 + tl) * ROWB + ks * 64 + q * 16);
      half8v a3 = *(const half8v*)(smB_ + (0  + tl) * ROWB + ks * 64 + q * 16);
      half8v a4 = *(const half8v*)(smB_ + (16 + tl) * ROWB + ks * 64 + q * 16);
      half8v a5 = *(const half8v*)(smB_ + (32 + tl) * ROWB + ks * 64 + q * 16);
#pragma unroll
      for (int t = 0; t < NT2; ++t) {
        half8v bf = pk7[(size_t)(((w16 * NT2 + t) * 16 + ks)) * 64 + lane];
        acc7[0][t] = __builtin_amdgcn_mfma_f32_16x16x32_f16(a0, bf, acc7[0][t], 0, 0, 0);
        acc7[1][t] = __builtin_amdgcn_mfma_f32_16x16x32_f16(a1, bf, acc7[1][t], 0, 0, 0);
        acc7[2][t] = __builtin_amdgcn_mfma_f32_16x16x32_f16(a2, bf, acc7[2][t], 0, 0, 0);
        acc7[3][t] = __builtin_amdgcn_mfma_f32_16x16x32_f16(a3, bf, acc7[3][t], 0, 0, 0);
        acc7[4][t] = __builtin_amdgcn_mfma_f32_16x16x32_f16(a4, bf, acc7[4][t], 0, 0, 0);
        acc7[5][t] = __builtin_amdgcn_mfma_f32_16x16x32_f16(a5, bf, acc7[5][t], 0, 0, 0);
      }
    }
    __builtin_amdgcn_s_setprio(0);
#pragma unroll
    for (int s = 0; s < 2; ++s) {
      int n0s = grp * 8 + s * 4;
#pragma unroll
      for (int t = 0; t < NT2; ++t) {
        int o2 = (w16 * NT2 + t) * 16 + tl;
        float hcv[4], mx[4], s1[4], s2[4];
#pragma unroll
        for (int g = 0; g < 4; ++g) {
          hcv[g] = __half2float(hc[((size_t)((b << 12) + n0s + g)) * O2 + o2]);
          mx[g] = -1e30f; s1[g] = 0.f; s2[g] = 0.f;
        }
#pragma unroll
        for (int mt = 0; mt < 3; ++mt)
#pragma unroll
          for (int r = 0; r < 4; ++r) {
            int gr = 16 * mt + 4 * q + r;
#pragma unroll
            for (int g = 0; g < 4; ++g) {
              if (gr >= 10 * g && gr < 10 * g + 10) {
                float v = acc7[mt + 3 * s][t][r] + hcv[g];
                mx[g] = fmaxf(mx[g], v);
                s1[g] += v;
                s2[g] = fmaf(v, v, s2[g]);
              }
            }
          }
#pragma unroll
        for (int g = 0; g < 4; ++g) {
          mx[g] = fmaxf(mx[g], __shfl_xor(mx[g], 16));
          mx[g] = fmaxf(mx[g], __shfl_xor(mx[g], 32));
        }
        float s1t = (s1[0] + s1[1]) + (s1[2] + s1[3]);
        float s2t = (s2[0] + s2[1]) + (s2[2] + s2[3]);
        s1t += __shfl_xor(s1t, 16); s1t += __shfl_xor(s1t, 32);
        s2t += __shfl_xor(s2t, 16); s2t += __shfl_xor(s2t, 32);
        if (q == 0) {
#pragma unroll
          for (int g = 0; g < 4; ++g)
            hmax[((size_t)((b << 12) + n0s + g)) * O2 + o2] = mx[g];
          atomicAdd(&A1[b * O2 + o2], s1t);
          atomicAdd(&A2[b * O2 + o2], s2t);
        }
      }
    }
  };

  __syncthreads();
  P1(0);
  __syncthreads();
  P23(0);
  __syncthreads();
  P4(0);
  __syncthreads();
  P6(0);
  __syncthreads();
  P1(1);
  __syncthreads();
  P23(1);
  __syncthreads();
  P4(1);
  __syncthreads();
  P6(1);
  __syncthreads();
  FU();
  __syncthreads();
  P7();
}

// ---------------- final conv via MFMA (atomic stats, inline norm of HMAX2) ----------------
__global__ __launch_bounds__(256) void gcn_final_mfma(
    const __half* __restrict__ featsT, const __half* __restrict__ f1T,
    const float* __restrict__ hmax2, const float* __restrict__ N1,
    const float* __restrict__ N2, const _Float16* __restrict__ PF,
    float* __restrict__ h3, float* __restrict__ A1, float* __restrict__ A2) {
  __shared__ __align__(16) char As[64 * 528];
  const int nb = blockIdx.x & 3, mb = blockIdx.x >> 2;   // mb 0..127
  const int tid = threadIdx.x;
  const int lane = tid & 63, w = tid >> 6, tl = lane & 15, q = lane >> 4;
  const int b = mb >> 6;
  const int nbase = (mb & 63) * 64;
  constexpr float invNK = 1.0f / 40960.0f;
  float4v acc[4];
#pragma unroll
  for (int t = 0; t < 4; ++t) acc[t] = (float4v){0.f, 0.f, 0.f, 0.f};
  const half8v* pf = (const half8v*)PF;
#pragma unroll 1
  for (int kc = 0; kc < 4; ++kc) {
    __syncthreads();
    for (int idx = tid; idx < 64 * 128; idx += 256) {
      int nl = idx >> 7, cp = idx & 127;
      size_t rowg = (size_t)(b << 12) + nbase + nl;
      __half2 v;
      if (kc == 0)      v = *(const __half2*)(featsT + rowg * 256 + cp * 2);
      else if (kc == 1) v = *(const __half2*)(f1T + rowg * 256 + cp * 2);
      else {
        int c0 = (kc == 2 ? 0 : 256) + cp * 2;
        float x0 = hmax2[rowg * 512 + c0];
        float x1 = hmax2[rowg * 512 + c0 + 1];
        int t0 = b * 512 + c0;
        float mu0 = N1[t0] * invNK;
        float var0 = N2[t0] * invNK - mu0 * mu0;
        float rs0 = __frsqrt_rn(var0 + 1e-5f);
        float mu1 = N1[t0 + 1] * invNK;
        float var1 = N2[t0 + 1] * invNK - mu1 * mu1;
        float rs1 = __frsqrt_rn(var1 + 1e-5f);
        float y0 = (x0 - mu0) * rs0; y0 = y0 > 0.f ? y0 : 0.2f * y0;
        float y1 = (x1 - mu1) * rs1; y1 = y1 > 0.f ? y1 : 0.2f * y1;
        v = __floats2half2_rn(y0, y1);
      }
      *(__half2*)(As + nl * 528 + cp * 4) = v;
    }
    __syncthreads();
#pragma unroll
    for (int ks = 0; ks < 8; ++ks) {
      int ksg = kc * 8 + ks;
      half8v a = *(const half8v*)(As + (w * 16 + tl) * 528 + ks * 64 + q * 16);
#pragma unroll
      for (int t = 0; t < 4; ++t) {
        half8v bf = pf[(size_t)(((nb * 4 + t) * 32 + ksg)) * 64 + lane];
        acc[t] = __builtin_amdgcn_mfma_f32_16x16x32_f16(a, bf, acc[t], 0, 0, 0);
      }
    }
  }
#pragma unroll
  for (int t = 0; t < 4; ++t) {
    int o = (nb * 4 + t) * 16 + tl;
    float s1 = 0.f, s2 = 0.f;
#pragma unroll
    for (int r = 0; r < 4; ++r) {
      float v = acc[t][r];
      int n = nbase + w * 16 + q * 4 + r;
      h3[((size_t)(b << 12) + n) * 256 + o] = v;
      s1 += v;
      s2 = fmaf(v, v, s2);
    }
    s1 += __shfl_xor(s1, 16); s1 += __shfl_xor(s1, 32);
    s2 += __shfl_xor(s2, 16); s2 += __shfl_xor(s2, 32);
    if (q == 0) {
      atomicAdd(&A1[b * 256 + o], s1);
      atomicAdd(&A2[b * 256 + o], s2);
    }
  }
}

// ---------------- final: transpose-norm h3 -> d_out, mu/rs inline ----------------
__global__ __launch_bounds__(256) void gcn_normT(const float* __restrict__ h3,
                                                 const float* __restrict__ A1,
                                                 const float* __restrict__ A2,
                                                 float* __restrict__ out) {
  __shared__ float tile[64][65];
  int x = blockIdx.x;
  int ob = x & 3, nb = (x >> 2) & 63, b = x >> 8;
  int n0 = nb * 64, o0 = ob * 64;
  for (int idx = threadIdx.x; idx < 4096; idx += 256) {
    int nl = idx >> 6, oc = idx & 63;
    tile[nl][oc] = h3[((size_t)(b << 12) + n0 + nl) * 256 + o0 + oc];
  }
  __syncthreads();
  constexpr float invN = 1.0f / 4096.0f;
  for (int idx = threadIdx.x; idx < 4096; idx += 256) {
    int ol = idx >> 6, nc = idx & 63;
    int t = b * 256 + o0 + ol;
    float mu = A1[t] * invN;
    float var = A2[t] * invN - mu * mu;
    float rs = __frsqrt_rn(var + 1e-5f);
    float v = (tile[nc][ol] - mu) * rs;
    v = v > 0.f ? v : 0.2f * v;
    out[((size_t)(b * 256 + o0 + ol) << 12) + n0 + nc] = v;
  }
}

// ---------------- launch ----------------
extern "C" void kernel_launch(void* const* d_in, const int* in_sizes, int n_in,
                              void* d_out, int out_size, void* d_ws, size_t ws_size,
                              hipStream_t stream) {
  (void)in_sizes; (void)n_in; (void)out_size; (void)ws_size;
  const float* coords  = (const float*)d_in[0];
  const float* feats   = (const float*)d_in[1];
  const float* W_lin1  = (const float*)d_in[2];
  const float* b_lin1  = (const float*)d_in[3];
  const float* W_lin2  = (const float*)d_in[4];
  const float* b_lin2  = (const float*)d_in[5];
  const float* W_conv1 = (const float*)d_in[6];
  const float* W_conv2 = (const float*)d_in[7];
  const float* W_conv3 = (const float*)d_in[8];
  char* ws = (char*)d_ws;

  float* A1_1    = (float*)(ws + OFF_A1_1);
  float* A2_1    = (float*)(ws + OFF_A2_1);
  float* A1_2    = (float*)(ws + OFF_A1_2);
  float* A2_2    = (float*)(ws + OFF_A2_2);
  float* A1_3    = (float*)(ws + OFF_A1_3);
  float* A2_3    = (float*)(ws + OFF_A2_3);
  float* F_MM    = (float*)(ws + OFF_MM);
  unsigned long long* KEYS = (unsigned long long*)(ws + OFF_KEYS);
  int* INDS      = (int*)(ws + OFF_INDS);
  _Float16* PK61 = (_Float16*)(ws + OFF_PK6_1);
  _Float16* PK62 = (_Float16*)(ws + OFF_PK6_2);
  _Float16* PK71 = (_Float16*)(ws + OFF_PK7_1);
  _Float16* PK72 = (_Float16*)(ws + OFF_PK7_2);
  float* WFOLD1  = (float*)(ws + OFF_WFOLD1);
  float* WFOLD2  = (float*)(ws + OFF_WFOLD2);
  _Float16* PC1  = (_Float16*)(ws + OFF_PC1);
  _Float16* PC2  = (_Float16*)(ws + OFF_PC2);
  float* BC1     = (float*)(ws + OFF_BC1);
  float* BC2     = (float*)(ws + OFF_BC2);
  __half* FEATST = (__half*)(ws + OFF_FEATST);
  __half* F1T    = (__half*)(ws + OFF_F1T);
  float* HMAX1   = (float*)(ws + OFF_HMAX1);
  float* HMAX2   = (float*)(ws + OFF_HMAX2);
  __half* HC1    = (__half*)(ws + OFF_HC1);
  __half* HC2    = (__half*)(ws + OFF_HC2);
  _Float16* PF3  = (_Float16*)(ws + OFF_PF3);
  float* H3      = (float*)(ws + OFF_H3);

  gcn_minmax<<<6, 256, 0, stream>>>(coords, F_MM);
  gcn_keys<<<32, 256, 0, stream>>>(coords, F_MM, KEYS, (float*)ws);
  gcn_prep<<<PREP_BLOCKS, 1024, 0, stream>>>(
      feats, FEATST, W_lin1, W_lin2, W_conv1, W_conv2, W_conv3,
      WFOLD1, WFOLD2, PK61, PK62, PK71, PK72, PF3);
  gcn_stageB<<<768, 256, 0, stream>>>(W_conv1, b_lin1, W_conv2, b_lin2,
                                      WFOLD1, WFOLD2, PC1, BC1, PC2, BC2);
  // sort (8 blocks) overlaps hc<256> (128 blocks x 4 tiles)
  gcn_sort_hc<<<SORTHC_BLOCKS, 1024, 0, stream>>>(KEYS, INDS, FEATST, PC1, BC1, HC1);

  // layer 1 (perm1 = [2,0,3,1])
  gcn_window<256><<<1024, 1024, 0, stream>>>(
      FEATST, INDS, PK61, PK71, HC1,
      HMAX1, A1_1, A2_1, 2, 0, 3, 1);

  // fused: normalize(HMAX1) -> F1T + hc<512>
  gcn_norm_hc512<<<1024, 256, 0, stream>>>(HMAX1, A1_1, A2_1, F1T, PC2, BC2, HC2);

  // layer 2 (perm2 = [1,3,0,2])
  gcn_window<512><<<1024, 1024, 0, stream>>>(
      F1T, INDS, PK62, PK72, HC2,
      HMAX2, A1_2, A2_2, 1, 3, 0, 2);

  // final conv (MFMA, inline norm of HMAX2) + transpose-norm
  gcn_final_mfma<<<512, 256, 0, stream>>>(FEATST, F1T, HMAX2, A1_2, A2_2,
                                          PF3, H3, A1_3, A2_3);
  gcn_normT<<<512, 256, 0, stream>>>(H3, A1_3, A2_3, (float*)d_out);
}

// Round 11
// 613.297 us; speedup vs baseline: 1.0324x; 1.0256x over previous
//
#include <hip/hip_runtime.h>
#include <hip/hip_fp16.h>

// =====================================================================
// GCN pipeline on MI355X, round 17:
//  - base = round-16 (629.0us verified).
//  - NEW 1: bitonic sort barrier fusion. For each phase k, the j<=4
//    sub-steps act within aligned 8-elem groups whose direction bit
//    (i & k) is constant -> one thread runs j=4,2,1 in registers with
//    ONE barrier (was 3). Same for k=4 (groups of 4, j=2,1). Barriers
//    78 -> 57; compare-exchange network identical (bit-exact output).
//  - NEW 2: gcn_keys + stat-zeroing folded into gcn_prep (blocks 0-7);
//    minmax still precedes. One fewer launch; keys hidden under prep.
//  - window kernels untouched.
// =====================================================================

typedef _Float16 half8v  __attribute__((ext_vector_type(8)));
typedef _Float16 half4v  __attribute__((ext_vector_type(4)));
typedef float    float4v __attribute__((ext_vector_type(4)));
typedef float    floatx2 __attribute__((ext_vector_type(2)));

union H4 { half4v v; __half2 h[2]; };
union F2H { floatx2 f; __half2 h[2]; };

// ---------------- workspace layout (bytes) ----------------
constexpr size_t OFF_A1_1   = 0;
constexpr size_t OFF_A2_1   = 2048;
constexpr size_t OFF_A1_2   = 4096;
constexpr size_t OFF_A2_2   = 8192;
constexpr size_t OFF_A1_3   = 12288;
constexpr size_t OFF_A2_3   = 14336;
constexpr size_t OFF_MM     = 16384;                        // 12 floats
constexpr size_t OFF_KEYS   = OFF_MM + 256;
constexpr size_t OFF_INDS   = OFF_KEYS + 8ull*4096*8;
constexpr size_t OFF_PK6_1  = OFF_INDS + 8ull*4096*10*4;    // 1 MB
constexpr size_t OFF_PK6_2  = OFF_PK6_1 + 512ull*1024*2;
constexpr size_t OFF_PK7_1  = OFF_PK6_2 + 512ull*1024*2;
constexpr size_t OFF_PK7_2  = OFF_PK7_1 + 256ull*512*2;
constexpr size_t OFF_WFOLD1 = OFF_PK7_2 + 512ull*512*2;
constexpr size_t OFF_WFOLD2 = OFF_WFOLD1 + 512ull*256*4;
constexpr size_t OFF_PC1    = OFF_WFOLD2 + 512ull*256*4;
constexpr size_t OFF_PC2    = OFF_PC1 + 256ull*256*2;
constexpr size_t OFF_BC1    = OFF_PC2 + 512ull*256*2;
constexpr size_t OFF_BC2    = OFF_BC1 + 1024;
constexpr size_t OFF_FEATST = OFF_BC2 + 2048;               // (B,N,256) fp16
constexpr size_t OFF_F1T    = OFF_FEATST + 2ull*4096*256*2; // (B,N,256) fp16
constexpr size_t OFF_HMAX1  = OFF_F1T   + 2ull*4096*256*2;  // (B,N,256) fp32
constexpr size_t OFF_HMAX2  = OFF_HMAX1 + 2ull*4096*256*4;  // (B,N,512) fp32
constexpr size_t OFF_HC1    = OFF_HMAX2 + 2ull*4096*512*4;  // fp16 (B*N,256)
constexpr size_t OFF_HC2    = OFF_HC1   + 8192ull*256*2;    // fp16 (B*N,512)
constexpr size_t OFF_PF3    = OFF_HC2   + 8192ull*512*2;    // packed Wc3
constexpr size_t WS_NEED    = OFF_PF3   + 256ull*1024*2;
constexpr size_t OFF_H3     = OFF_HMAX1;   // hmax1 dead after norm_hc512

// ---------------- helpers ----------------
__device__ __forceinline__ int gcn_quant1(float c, float cmin, float scale) {
  float q = floorf(__fmul_rn(__fsub_rn(c, cmin), scale));
  q = fminf(fmaxf(q, 0.0f), 1023.0f);
  return (int)q;
}

__device__ __forceinline__ unsigned int gcn_morton3(int x, int y, int z) {
  unsigned int key = 0u;
#pragma unroll
  for (int b = 0; b < 10; ++b) {
    key |= ((unsigned)((x >> b) & 1)) << (3 * b + 2);
    key |= ((unsigned)((y >> b) & 1)) << (3 * b + 1);
    key |= ((unsigned)((z >> b) & 1)) << (3 * b + 0);
  }
  return key;
}

__device__ __forceinline__ unsigned int gcn_hilbert3(int x, int y, int z) {
  int X0 = x, X1 = y, X2 = z;
  for (int Q = 512; Q > 1; Q >>= 1) {
    int P = Q - 1;
    if (X0 & Q) X0 ^= P;
    {
      int t = (X0 ^ X1) & P;
      if (X1 & Q) { X0 ^= P; } else { X0 ^= t; X1 ^= t; }
    }
    {
      int t = (X0 ^ X2) & P;
      if (X2 & Q) { X0 ^= P; } else { X0 ^= t; X2 ^= t; }
    }
  }
  X1 ^= X0;
  X2 ^= X1;
  int t = 0;
  for (int Q = 512; Q > 1; Q >>= 1)
    if (X2 & Q) t ^= (Q - 1);
  X0 ^= t; X1 ^= t; X2 ^= t;
  unsigned int key = 0u;
#pragma unroll
  for (int b = 9; b >= 0; --b) {
    key = (key << 1) | (unsigned)((X0 >> b) & 1);
    key = (key << 1) | (unsigned)((X1 >> b) & 1);
    key = (key << 1) | (unsigned)((X2 >> b) & 1);
  }
  return key;
}

// ---------------- device bodies for fused prep stages ----------------
__device__ void dev_foldF(const float* __restrict__ W, float* __restrict__ Wf, int i) {
  int o = i >> 8, c = i & 255;
  float4 w = ((const float4*)W)[(size_t)o * 512 + c];
  Wf[i] = w.x + w.y + w.z + w.w;
}

__device__ void dev_pack6(const float* __restrict__ W, _Float16* __restrict__ P, int i) {
  int lane = i & 63, ks = (i >> 6) & 31, nt = i >> 11;
  int tl = lane & 15, q = lane >> 4;
  int o = nt * 16 + tl;
  _Float16 tmp[8];
#pragma unroll
  for (int j = 0; j < 8; ++j) {
    int k = ks * 32 + q * 8 + j;
    int hp = k >> 9, r = k & 511, m = r >> 7, cl = r & 127;
    int col = 1024 + 4 * (128 * hp + cl) + m;
    tmp[j] = (_Float16)W[(size_t)o * 2048 + col];
  }
  *(half8v*)(P + (size_t)i * 8) = *(half8v*)tmp;
}

__device__ void dev_pack7(const float* __restrict__ W, _Float16* __restrict__ P, int i) {
  int lane = i & 63, ks = (i >> 6) & 15, nt = i >> 10;
  int tl = lane & 15, q = lane >> 4;
  int o2 = nt * 16 + tl;
  int c2 = ks * 32 + q * 8;
  _Float16 tmp[8];
#pragma unroll
  for (int j = 0; j < 8; ++j)
    tmp[j] = (_Float16)W[(size_t)o2 * 512 + c2 + j];
  *(half8v*)(P + (size_t)i * 8) = *(half8v*)tmp;
}

__device__ void dev_packF(const float* __restrict__ W, _Float16* __restrict__ P, int i) {
  int lane = i & 63, ksg = (i >> 6) & 31, nt = i >> 11;
  int tl = lane & 15, q = lane >> 4;
  int o = nt * 16 + tl;
  _Float16 tmp[8];
#pragma unroll
  for (int j = 0; j < 8; ++j)
    tmp[j] = (_Float16)W[(size_t)o * 1024 + ksg * 32 + q * 8 + j];
  *(half8v*)(P + (size_t)i * 8) = *(half8v*)tmp;
}

// Bitonic sort with fused register-resident j<=4 steps.
// Network identical to the classic form; for phase k, sub-steps with
// j<=4 act within aligned 8-elem groups whose direction (i&k) is
// constant -> 1 barrier instead of 3.
__device__ void dev_sort(const unsigned long long* __restrict__ keys,
                         int* __restrict__ inds, int g, int tid,
                         unsigned long long* a) {
  for (int i = tid; i < 4096; i += 1024) a[i] = keys[(size_t)g * 4096 + i];
  __syncthreads();
  // phase k=2 (j=1): pairs (2t, 2t+1), up = ((2t)&2)==0
  for (int t = tid; t < 2048; t += 1024) {
    int i = 2 * t;
    bool up = (i & 2) == 0;
    unsigned long long x = a[i], y = a[i + 1];
    if ((x > y) == up) { a[i] = y; a[i + 1] = x; }
  }
  __syncthreads();
  // phase k=4 (j=2,1 fused): groups of 4, direction (base&4)
  {
    int base = tid * 4;
    bool up = (base & 4) == 0;
    unsigned long long v0 = a[base], v1 = a[base + 1],
                       v2 = a[base + 2], v3 = a[base + 3];
    unsigned long long t0;
    if ((v0 > v2) == up) { t0 = v0; v0 = v2; v2 = t0; }
    if ((v1 > v3) == up) { t0 = v1; v1 = v3; v3 = t0; }
    if ((v0 > v1) == up) { t0 = v0; v0 = v1; v1 = t0; }
    if ((v2 > v3) == up) { t0 = v2; v2 = v3; v3 = t0; }
    a[base] = v0; a[base + 1] = v1; a[base + 2] = v2; a[base + 3] = v3;
  }
  __syncthreads();
  // phases k>=8: LDS steps for j>=8, then fused j=4,2,1 in registers
  for (int k = 8; k <= 4096; k <<= 1) {
    for (int j = k >> 1; j >= 8; j >>= 1) {
      for (int t = tid; t < 2048; t += 1024) {
        int i = 2 * t - (t & (j - 1));
        int p = i + j;
        bool up = (i & k) == 0;
        unsigned long long x = a[i], y = a[p];
        if ((x > y) == up) { a[i] = y; a[p] = x; }
      }
      __syncthreads();
    }
    if (tid < 512) {
      int base = tid * 8;
      bool up = (base & k) == 0;
      unsigned long long v[8], t0;
#pragma unroll
      for (int e = 0; e < 8; ++e) v[e] = a[base + e];
#pragma unroll
      for (int e = 0; e < 4; ++e)
        if ((v[e] > v[e + 4]) == up) { t0 = v[e]; v[e] = v[e + 4]; v[e + 4] = t0; }
#pragma unroll
      for (int h = 0; h < 8; h += 4)
#pragma unroll
        for (int e = 0; e < 2; ++e)
          if ((v[h + e] > v[h + e + 2]) == up) {
            t0 = v[h + e]; v[h + e] = v[h + e + 2]; v[h + e + 2] = t0;
          }
#pragma unroll
      for (int h = 0; h < 8; h += 2)
        if ((v[h] > v[h + 1]) == up) { t0 = v[h]; v[h] = v[h + 1]; v[h + 1] = t0; }
#pragma unroll
      for (int e = 0; e < 8; ++e) a[base + e] = v[e];
    }
    __syncthreads();
  }
  for (int i = tid; i < 4096; i += 1024) {
    int start = i - 5; if (start < 0) start = 0;
    int endm1 = i + 5; if (endm1 > 4095) endm1 = 4095;
#pragma unroll
    for (int kk = 0; kk < 10; ++kk) {
      int pos = start + kk; if (pos > endm1) pos = endm1;
      inds[((size_t)g * 4096 + i) * 10 + kk] = (int)(a[pos] & 0xFFFULL);
    }
  }
}

__device__ void dev_transpose(const float* __restrict__ feats, __half* __restrict__ fT,
                              int vblk, int t256, float* tt) {   // tt: 32*33 floats
  int cb = vblk & 7, nb = (vblk >> 3) & 127, b = vblk >> 10;
  int tx = t256 & 31, ty = t256 >> 5;
#pragma unroll
  for (int i = 0; i < 4; ++i) {
    int c = cb * 32 + ty + i * 8;
    tt[(ty + i * 8) * 33 + tx] = feats[((size_t)(b * 256 + c) << 12) + nb * 32 + tx];
  }
  __syncthreads();
  if (tx < 16) {
#pragma unroll
    for (int i = 0; i < 4; ++i) {
      int nl = ty + i * 8;
      int n = nb * 32 + nl;
      __half2 hv = __floats2half2_rn(tt[(2 * tx) * 33 + nl], tt[(2 * tx + 1) * 33 + nl]);
      *(__half2*)(fT + ((size_t)((b << 12) + n)) * 256 + cb * 32 + 2 * tx) = hv;
    }
  }
}

// hc<256> tile body (256-thread sub-tile; As = 33792 B per sub-tile)
__device__ void dev_hc256(const __half* __restrict__ src,
                          const _Float16* __restrict__ PC,
                          const float* __restrict__ bc,
                          __half* __restrict__ out, int tile, int tid,
                          _Float16* As) {
  int nb = tile & 3, mb = tile >> 2;
  const __half2* s2 = (const __half2*)(src + (size_t)mb * 64 * 256);
  for (int idx = tid; idx < 64 * 128; idx += 256) {
    int row = idx >> 7, cp = idx & 127;
    __half2 v = s2[row * 128 + cp];
    *(__half2*)((char*)As + row * 528 + cp * 4) = v;
  }
  __syncthreads();
  int lane = tid & 63, w = tid >> 6, tl = lane & 15, q = lane >> 4;
  float4v acc[4];
#pragma unroll
  for (int t = 0; t < 4; ++t) acc[t] = (float4v){0.f, 0.f, 0.f, 0.f};
  const half8v* pc = (const half8v*)PC;
#pragma unroll
  for (int ks = 0; ks < 8; ++ks) {
    half8v a = *(const half8v*)((const char*)As + (w * 16 + tl) * 528 + ks * 64 + q * 16);
#pragma unroll
    for (int t = 0; t < 4; ++t) {
      half8v bf = pc[(size_t)(((nb * 4 + t) * 8 + ks)) * 64 + lane];
      acc[t] = __builtin_amdgcn_mfma_f32_16x16x32_f16(a, bf, acc[t], 0, 0, 0);
    }
  }
#pragma unroll
  for (int t = 0; t < 4; ++t) {
    int o = (nb * 4 + t) * 16 + tl;
    float bb = bc[o];
#pragma unroll
    for (int r = 0; r < 4; ++r) {
      int row = mb * 64 + w * 16 + q * 4 + r;
      out[(size_t)row * 256 + o] = __float2half(acc[t][r] + bb);
    }
  }
}

// keys body (1024-thread block handles 1024 idx)
__device__ void dev_keys(const float* __restrict__ coords, const float* __restrict__ mm,
                         unsigned long long* __restrict__ keys, int idx) {
  int b = idx >> 12, n = idx & 4095;
  const float* cb = coords + (size_t)b * 3 * 4096;
  int q0 = gcn_quant1(cb[n],        mm[b * 3 + 0], mm[6 + b * 3 + 0]);
  int q1 = gcn_quant1(cb[4096 + n], mm[b * 3 + 1], mm[6 + b * 3 + 1]);
  int q2 = gcn_quant1(cb[8192 + n], mm[b * 3 + 2], mm[6 + b * 3 + 2]);
  unsigned long long nn = (unsigned long long)(unsigned)n;
  size_t base = ((size_t)b * 4) * 4096 + n;
  keys[base]         = ((unsigned long long)gcn_morton3(q0, q1, q2) << 12) | nn;
  keys[base + 4096]  = ((unsigned long long)gcn_morton3(q1, q0, q2) << 12) | nn;
  keys[base + 8192]  = ((unsigned long long)gcn_hilbert3(q0, q1, q2) << 12) | nn;
  keys[base + 12288] = ((unsigned long long)gcn_hilbert3(q1, q0, q2) << 12) | nn;
}

// ---------------- prep: keys + zero-stats + transpose + folds + packs ----------------
__global__ __launch_bounds__(1024) void gcn_prep(
    const float* __restrict__ coords, const float* __restrict__ mm,
    unsigned long long* __restrict__ keys, float* __restrict__ AZ,
    const float* __restrict__ feats, __half* __restrict__ fT,
    const float* __restrict__ W_lin1, const float* __restrict__ W_lin2,
    const float* __restrict__ W_conv1, const float* __restrict__ W_conv2,
    const float* __restrict__ W_conv3,
    float* __restrict__ WFOLD1, float* __restrict__ WFOLD2,
    _Float16* __restrict__ PK61, _Float16* __restrict__ PK62,
    _Float16* __restrict__ PK71, _Float16* __restrict__ PK72,
    _Float16* __restrict__ PF3) {
  __shared__ __align__(16) char smA[32768];
  int blk = blockIdx.x, tid = threadIdx.x;
  if (blk < 8) {
    if (blk < 4) AZ[blk * 1024 + tid] = 0.f;
    dev_keys(coords, mm, keys, blk * 1024 + tid);
    return;
  }
  blk -= 8;
  if (blk < 512) {
    float* tt = (float*)smA + (tid >> 8) * (32 * 33);
    dev_transpose(feats, fT, blk * 4 + (tid >> 8), tid & 255, tt);
    return;
  }
  blk -= 512;
  if (blk < 128) { dev_foldF(W_lin1, WFOLD1, blk * 1024 + tid); return; }
  blk -= 128;
  if (blk < 128) { dev_foldF(W_lin2, WFOLD2, blk * 1024 + tid); return; }
  blk -= 128;
  if (blk < 64)  { dev_pack6(W_lin1, PK61, blk * 1024 + tid); return; }
  blk -= 64;
  if (blk < 64)  { dev_pack6(W_lin2, PK62, blk * 1024 + tid); return; }
  blk -= 64;
  if (blk < 16)  { dev_pack7(W_conv1, PK71, blk * 1024 + tid); return; }
  blk -= 16;
  if (blk < 32)  { dev_pack7(W_conv2, PK72, blk * 1024 + tid); return; }
  blk -= 32;
  dev_packF(W_conv3, PF3, blk * 1024 + tid);
}
constexpr int PREP_BLOCKS = 8 + 512 + 128 + 128 + 64 + 64 + 16 + 32 + 32;  // 984

// ---------------- fused sort + hc<256> ----------------
__global__ __launch_bounds__(1024) void gcn_sort_hc(
    const unsigned long long* __restrict__ keys, int* __restrict__ inds,
    const __half* __restrict__ src, const _Float16* __restrict__ PC,
    const float* __restrict__ bc, __half* __restrict__ out) {
  __shared__ __align__(16) char sm[135168];
  int blk = blockIdx.x, tid = threadIdx.x;
  if (blk < 8) { dev_sort(keys, inds, blk, tid, (unsigned long long*)sm); return; }
  int tile = (blk - 8) * 4 + (tid >> 8);
  dev_hc256(src, PC, bc, out, tile, tid & 255,
            (_Float16*)(sm + (size_t)(tid >> 8) * 33792));
}
constexpr int SORTHC_BLOCKS = 8 + 128;

// ---------------- stage B: wcomb + direct PC pack ----------------
__device__ void dev_wcomb_pack(const float* __restrict__ Wc, const float* __restrict__ blin,
                               const float* __restrict__ WfoldF, _Float16* __restrict__ PC,
                               float* __restrict__ bc, int o2, float* wrow) {
  int tid = threadIdx.x;
  wrow[tid] = Wc[(size_t)o2 * 512 + tid];
  wrow[tid + 256] = Wc[(size_t)o2 * 512 + tid + 256];
  __syncthreads();
  float acc = 0.f;
  for (int o = 0; o < 512; ++o)
    acc = fmaf(wrow[o], WfoldF[(size_t)o * 256 + tid], acc);
  int n = o2, c = tid;
  size_t pidx =
      ((size_t)(n >> 4) * 512 + (size_t)((c >> 5) * 64 + ((c >> 3) & 3) * 16 + (n & 15))) * 8
      + (c & 7);
  PC[pidx] = (_Float16)acc;
  if (tid == 0) {
    float s = 0.f;
    for (int o = 0; o < 512; ++o) s += wrow[o] * blin[o];
    bc[o2] = s;
  }
}

__global__ __launch_bounds__(256) void gcn_stageB(
    const float* __restrict__ Wc1, const float* __restrict__ b1,
    const float* __restrict__ Wc2, const float* __restrict__ b2,
    const float* __restrict__ WF1, const float* __restrict__ WF2,
    _Float16* __restrict__ PC1, float* __restrict__ BC1,
    _Float16* __restrict__ PC2, float* __restrict__ BC2) {
  __shared__ float wrow[512];
  int blk = blockIdx.x;
  if (blk < 256) dev_wcomb_pack(Wc1, b1, WF1, PC1, BC1, blk, wrow);
  else           dev_wcomb_pack(Wc2, b2, WF2, PC2, BC2, blk - 256, wrow);
}

// ---------------- quantize prep ----------------
__global__ void gcn_minmax(const float* __restrict__ coords, float* __restrict__ mm) {
  __shared__ float slo[256], shi[256];
  int d = blockIdx.x, tid = threadIdx.x;
  float lo = 1e30f, hi = -1e30f;
  for (int i = tid; i < 4096; i += 256) {
    float v = coords[(size_t)d * 4096 + i];
    lo = fminf(lo, v);
    hi = fmaxf(hi, v);
  }
  slo[tid] = lo; shi[tid] = hi;
  __syncthreads();
  for (int s = 128; s > 0; s >>= 1) {
    if (tid < s) {
      slo[tid] = fminf(slo[tid], slo[tid + s]);
      shi[tid] = fmaxf(shi[tid], shi[tid + s]);
    }
    __syncthreads();
  }
  if (tid == 0) {
    mm[d] = slo[0];
    mm[6 + d] = 1023.0f / ((shi[0] - slo[0]) + 1e-6f);
  }
}

// ---------------- fused norm(layer1) + hc<512> ----------------
__global__ __launch_bounds__(256) void gcn_norm_hc512(
    const float* __restrict__ hmax1, const float* __restrict__ A1,
    const float* __restrict__ A2, __half* __restrict__ f1T,
    const _Float16* __restrict__ PC, const float* __restrict__ bc,
    __half* __restrict__ out) {
  __shared__ __align__(16) _Float16 As[64 * 264];
  int nb = blockIdx.x & 7, mb = blockIdx.x >> 3;
  int tid = threadIdx.x;
  int bb = mb >> 6;
  constexpr float invNK = 1.0f / 40960.0f;
  const float* src = hmax1 + (size_t)mb * 64 * 256;
  for (int idx = tid; idx < 64 * 128; idx += 256) {
    int row = idx >> 7, cp = idx & 127;
    int c0 = cp * 2;
    float x0 = src[row * 256 + c0];
    float x1 = src[row * 256 + c0 + 1];
    int t0 = bb * 256 + c0;
    float mu0 = A1[t0] * invNK;
    float var0 = A2[t0] * invNK - mu0 * mu0;
    float rs0 = __frsqrt_rn(var0 + 1e-5f);
    float mu1 = A1[t0 + 1] * invNK;
    float var1 = A2[t0 + 1] * invNK - mu1 * mu1;
    float rs1 = __frsqrt_rn(var1 + 1e-5f);
    float y0 = (x0 - mu0) * rs0; y0 = y0 > 0.f ? y0 : 0.2f * y0;
    float y1 = (x1 - mu1) * rs1; y1 = y1 > 0.f ? y1 : 0.2f * y1;
    __half2 hv = __floats2half2_rn(y0, y1);
    *(__half2*)((char*)As + row * 528 + cp * 4) = hv;
    if (nb == 0)
      *(__half2*)(f1T + ((size_t)mb * 64 + row) * 256 + c0) = hv;
  }
  __syncthreads();
  int lane = tid & 63, w = tid >> 6, tl = lane & 15, q = lane >> 4;
  float4v acc[4];
#pragma unroll
  for (int t = 0; t < 4; ++t) acc[t] = (float4v){0.f, 0.f, 0.f, 0.f};
  const half8v* pc = (const half8v*)PC;
#pragma unroll
  for (int ks = 0; ks < 8; ++ks) {
    half8v a = *(const half8v*)((const char*)As + (w * 16 + tl) * 528 + ks * 64 + q * 16);
#pragma unroll
    for (int t = 0; t < 4; ++t) {
      half8v bf = pc[(size_t)(((nb * 4 + t) * 8 + ks)) * 64 + lane];
      acc[t] = __builtin_amdgcn_mfma_f32_16x16x32_f16(a, bf, acc[t], 0, 0, 0);
    }
  }
#pragma unroll
  for (int t = 0; t < 4; ++t) {
    int o = (nb * 4 + t) * 16 + tl;
    float bv = bc[o];
#pragma unroll
    for (int r = 0; r < 4; ++r) {
      int row = mb * 64 + w * 16 + q * 4 + r;
      out[(size_t)row * 512 + o] = __float2half(acc[t][r] + bv);
    }
  }
}

// ---------------- fused 4-window MFMA kernel, joint P6/P7 ----------------
constexpr int ROWB   = 1040;
constexpr int SM_SC  = 49920;
constexpr int SM_GRP = 53120;

__device__ __forceinline__ int& idx_at(char* smem, int j) {
  return ((int*)(smem + (j >> 2) * ROWB + 1024))[j & 3];
}

template <int O2>
__global__ __launch_bounds__(1024, 4) void gcn_window(
    const __half* __restrict__ fT, const int* __restrict__ inds,
    const _Float16* __restrict__ PK6, const _Float16* __restrict__ PK7,
    const __half* __restrict__ hc,
    float* __restrict__ hmax, float* __restrict__ A1, float* __restrict__ A2,
    int p0, int p1, int p2, int p3) {
  __shared__ __align__(16) char smem_all[2 * SM_GRP];

  const int tid  = threadIdx.x;
  const int G    = tid >> 9;
  const int tid8 = tid & 511;
  const int lane = tid & 63;
  const int w8   = tid8 >> 6;
  const int w16  = tid >> 6;
  const int tl = lane & 15, q = lane >> 4;
  const int swz = (blockIdx.x & 7) * 128 + (blockIdx.x >> 3);
  const int b   = swz >> 9;
  const int grp = swz & 511;
  const int n0  = grp * 8 + G * 4;
  char* sm  = smem_all + G * SM_GRP;
  char* smA_ = smem_all;
  char* smB_ = smem_all + SM_GRP;
  __half2* sch = (__half2*)(sm + SM_SC);
  const __half* fTb = fT + ((size_t)(b << 12)) * 256;

  if (tid8 < 160) {
    int g = tid8 / 40, rem = tid8 % 40, m = rem / 10, kk = rem % 10;
    int meth = (m == 0) ? p0 : (m == 1) ? p1 : (m == 2) ? p2 : p3;
    idx_at(sm, tid8) = inds[((size_t)((b * 4 + meth) << 12) + n0 + g) * 10 + kk];
  }

  float4v acc6[6][2];
#pragma unroll
  for (int f = 0; f < 6; ++f)
#pragma unroll
    for (int t = 0; t < 2; ++t) acc6[f][t] = (float4v){0.f, 0.f, 0.f, 0.f};

  const half8v* pk6 = (const half8v*)PK6;
  const half8v* pk7 = (const half8v*)PK7;

  auto P1 = [&](int hp) {
    const int l32 = lane & 31;
    const int kkh = lane >> 5;
    const int g = w8 >> 1;
    const half4v cv =
        *(const half4v*)(fTb + (size_t)(n0 + g) * 256 + hp * 128 + 4 * l32);
#pragma unroll
    for (int s = 0; s < 2; ++s) {
      const int m = (w8 * 2 + s) & 3;
      const int jb = (g * 4 + m) * 10;
#pragma unroll
      for (int kk2 = 0; kk2 < 10; kk2 += 2) {
        int kk = kk2 + kkh;
        int id = idx_at(sm, jb + kk);
        half4v v = *(const half4v*)(fTb + (size_t)id * 256 + hp * 128 + 4 * l32);
        *(half4v*)(sm + (g * 10 + kk) * ROWB + m * 256 + 8 * l32) = v - cv;
      }
    }
  };

  auto P23 = [&](int hp) {
    (void)hp;
    int g2 = w8 >> 1, hh = w8 & 1;
    float4v as = {0.f, 0.f, 0.f, 0.f};
    const char* rowbase = sm + (g2 * 10 + tl) * ROWB + hh * 128;
#pragma unroll
    for (int m4 = 0; m4 < 4; ++m4) {
      half8v a0 = *(const half8v*)(rowbase + m4 * 256 + q * 16);
      half8v a1 = *(const half8v*)(rowbase + m4 * 256 + 64 + q * 16);
      as = __builtin_amdgcn_mfma_f32_16x16x32_f16(a0, a0, as, 0, 0, 0);
      as = __builtin_amdgcn_mfma_f32_16x16x32_f16(a1, a1, as, 0, 0, 0);
    }
    bool vt = (tl < 10);
    __half2* scb = sch + (g2 * 2 + hh) * 100;
#pragma unroll
    for (int r = 0; r < 4; ++r) {
      float v = vt ? as[r] * 0.0625f : -1e30f;
      float m = v;
      m = fmaxf(m, __shfl_xor(m, 1));
      m = fmaxf(m, __shfl_xor(m, 2));
      m = fmaxf(m, __shfl_xor(m, 4));
      m = fmaxf(m, __shfl_xor(m, 8));
      float e = vt ? __expf(v - m) : 0.f;
      float su = e;
      su += __shfl_xor(su, 1);
      su += __shfl_xor(su, 2);
      su += __shfl_xor(su, 4);
      su += __shfl_xor(su, 8);
      float ar = e / su;
      int row = q * 4 + r;
      if (row < 10 && vt) scb[row * 10 + tl] = __floats2half2_rn(ar, ar);
    }
  };

  auto P4 = [&](int hp) {
    (void)hp;
    const int g4 = tid8 >> 7, c4 = tid8 & 127;
    const floatx2* ar2 = (const floatx2*)(sch + (g4 * 2 + ((c4 >> 4) & 1)) * 100);
    __half2 x0[10], x1[10];
#pragma unroll
    for (int j = 0; j < 10; ++j) {
      H4 u;
      u.v = *(const half4v*)(sm + (g4 * 10 + j) * ROWB + 8 * c4);
      x0[j] = u.h[0];
      x1[j] = u.h[1];
    }
#pragma unroll
    for (int kk = 0; kk < 10; ++kk) {
      __half2 a0 = __floats2half2_rn(0.f, 0.f), a1 = a0;
#pragma unroll
      for (int j = 0; j < 10; j += 2) {
        F2H wv;
        wv.f = ar2[kk * 5 + (j >> 1)];
        a0 = __hfma2(wv.h[0], x0[j], a0);
        a1 = __hfma2(wv.h[0], x1[j], a1);
        a0 = __hfma2(wv.h[1], x0[j + 1], a0);
        a1 = __hfma2(wv.h[1], x1[j + 1], a1);
      }
      H4 o;
      o.h[0] = a0;
      o.h[1] = a1;
      *(half4v*)(sm + (g4 * 10 + kk) * ROWB + 8 * c4) = o.v;
    }
  };

  auto P6 = [&](int hp) {
    __builtin_amdgcn_s_setprio(1);
#pragma unroll 2
    for (int ks = 0; ks < 16; ++ks) {
      half8v a0 = *(const half8v*)(smA_ + (0  + tl) * ROWB + ks * 64 + q * 16);
      half8v a1 = *(const half8v*)(smA_ + (16 + tl) * ROWB + ks * 64 + q * 16);
      half8v a2 = *(const half8v*)(smA_ + (32 + tl) * ROWB + ks * 64 + q * 16);
      half8v a3 = *(const half8v*)(smB_ + (0  + tl) * ROWB + ks * 64 + q * 16);
      half8v a4 = *(const half8v*)(smB_ + (16 + tl) * ROWB + ks * 64 + q * 16);
      half8v a5 = *(const half8v*)(smB_ + (32 + tl) * ROWB + ks * 64 + q * 16);
#pragma unroll
      for (int t = 0; t < 2; ++t) {
        half8v bf = pk6[(size_t)(((w16 * 2 + t) * 32 + hp * 16 + ks)) * 64 + lane];
        acc6[0][t] = __builtin_amdgcn_mfma_f32_16x16x32_f16(a0, bf, acc6[0][t], 0, 0, 0);
        acc6[1][t] = __builtin_amdgcn_mfma_f32_16x16x32_f16(a1, bf, acc6[1][t], 0, 0, 0);
        acc6[2][t] = __builtin_amdgcn_mfma_f32_16x16x32_f16(a2, bf, acc6[2][t], 0, 0, 0);
        acc6[3][t] = __builtin_amdgcn_mfma_f32_16x16x32_f16(a3, bf, acc6[3][t], 0, 0, 0);
        acc6[4][t] = __builtin_amdgcn_mfma_f32_16x16x32_f16(a4, bf, acc6[4][t], 0, 0, 0);
        acc6[5][t] = __builtin_amdgcn_mfma_f32_16x16x32_f16(a5, bf, acc6[5][t], 0, 0, 0);
      }
    }
    __builtin_amdgcn_s_setprio(0);
  };

  auto FU = [&]() {
#pragma unroll
    for (int s = 0; s < 2; ++s) {
      char* ss = (s == 0) ? smA_ : smB_;
#pragma unroll
      for (int mt = 0; mt < 3; ++mt)
#pragma unroll
        for (int t = 0; t < 2; ++t) {
          int o = (w16 * 2 + t) * 16 + tl;
#pragma unroll
          for (int r = 0; r < 4; ++r) {
            int row = 16 * mt + q * 4 + r;
            *(__half*)(ss + row * ROWB + o * 2) = __float2half(acc6[mt + 3 * s][t][r]);
          }
        }
    }
  };

  auto P7 = [&]() {
    constexpr int NT2 = O2 / 256;
    float4v acc7[6][NT2];
#pragma unroll
    for (int f = 0; f < 6; ++f)
#pragma unroll
      for (int t = 0; t < NT2; ++t) acc7[f][t] = (float4v){0.f, 0.f, 0.f, 0.f};
    __builtin_amdgcn_s_setprio(1);
#pragma unroll 2
    for (int ks = 0; ks < 16; ++ks) {
      half8v a0 = *(const half8v*)(smA_ + (0  + tl) * ROWB + ks * 64 + q * 16);
      half8v a1 = *(const half8v*)(smA_ + (16 + tl) * ROWB + ks * 64 + q * 16);
      half8v a2 = *(const half8v*)(smA_ + (32 + tl) * ROWB + ks * 64 + q * 16);
      half8v a3 = *(const half8v*)(smB_ + (0  + tl) * ROWB + ks * 64 + q * 16);
      half8v a4 = *(const half8v*)(smB_ + (16 + tl) * ROWB + ks * 64 + q * 16);
      half8v a5 = *(const half8v*)(smB_ + (32 + tl) * ROWB + ks * 64 + q * 16);
#pragma unroll
      for (int t = 0; t < NT2; ++t) {
        half8v bf = pk7[(size_t)(((w16 * NT2 + t) * 16 + ks)) * 64 + lane];
        acc7[0][t] = __builtin_amdgcn_mfma_f32_16x16x32_f16(a0, bf, acc7[0][t], 0, 0, 0);
        acc7[1][t] = __builtin_amdgcn_mfma_f32_16x16x32_f16(a1, bf, acc7[1][t], 0, 0, 0);
        acc7[2][t] = __builtin_amdgcn_mfma_f32_16x16x32_f16(a2, bf, acc7[2][t], 0, 0, 0);
        acc7[3][t] = __builtin_amdgcn_mfma_f32_16x16x32_f16(a3, bf, acc7[3][t], 0, 0, 0);
        acc7[4][t] = __builtin_amdgcn_mfma_f32_16x16x32_f16(a4, bf, acc7[4][t], 0, 0, 0);
        acc7[5][t] = __builtin_amdgcn_mfma_f32_16x16x32_f16(a5, bf, acc7[5][t], 0, 0, 0);
      }
    }
    __builtin_amdgcn_s_setprio(0);
#pragma unroll
    for (int s = 0; s < 2; ++s) {
      int n0s = grp * 8 + s * 4;
#pragma unroll
      for (int t = 0; t < NT2; ++t) {
        int o2 = (w16 * NT2 + t) * 16 + tl;
        float hcv[4], mx[4], s1[4], s2[4];
#pragma unroll
        for (int g = 0; g < 4; ++g) {
          hcv[g] = __half2float(hc[((size_t)((b << 12) + n0s + g)) * O2 + o2]);
          mx[g] = -1e30f; s1[g] = 0.f; s2[g] = 0.f;
        }
#pragma unroll
        for (int mt = 0; mt < 3; ++mt)
#pragma unroll
          for (int r = 0; r < 4; ++r) {
            int gr = 16 * mt + 4 * q + r;
#pragma unroll
            for (int g = 0; g < 4; ++g) {
              if (gr >= 10 * g && gr < 10 * g + 10) {
                float v = acc7[mt + 3 * s][t][r] + hcv[g];
                mx[g] = fmaxf(mx[g], v);
                s1[g] += v;
                s2[g] = fmaf(v, v, s2[g]);
              }
            }
          }
#pragma unroll
        for (int g = 0; g < 4; ++g) {
          mx[g] = fmaxf(mx[g], __shfl_xor(mx[g], 16));
          mx[g] = fmaxf(mx[g], __shfl_xor(mx[g], 32));
        }
        float s1t = (s1[0] + s1[1]) + (s1[2] + s1[3]);
        float s2t = (s2[0] + s2[1]) + (s2[2] + s2[3]);
        s1t += __shfl_xor(s1t, 16); s1t += __shfl_xor(s1t, 32);
        s2t += __shfl_xor(s2t, 16); s2t += __shfl_xor(s2t, 32);
        if (q == 0) {
#pragma unroll
          for (int g = 0; g < 4; ++g)
            hmax[((size_t)((b << 12) + n0s + g)) * O2 + o2] = mx[g];
          atomicAdd(&A1[b * O2 + o2], s1t);
          atomicAdd(&A2[b * O2 + o2], s2t);
        }
      }
    }
  };

  __syncthreads();
  P1(0);
  __syncthreads();
  P23(0);
  __syncthreads();
  P4(0);
  __syncthreads();
  P6(0);
  __syncthreads();
  P1(1);
  __syncthreads();
  P23(1);
  __syncthreads();
  P4(1);
  __syncthreads();
  P6(1);
  __syncthreads();
  FU();
  __syncthreads();
  P7();
}

// ---------------- final conv via MFMA (atomic stats, inline norm of HMAX2) ----------------
__global__ __launch_bounds__(256) void gcn_final_mfma(
    const __half* __restrict__ featsT, const __half* __restrict__ f1T,
    const float* __restrict__ hmax2, const float* __restrict__ N1,
    const float* __restrict__ N2, const _Float16* __restrict__ PF,
    float* __restrict__ h3, float* __restrict__ A1, float* __restrict__ A2) {
  __shared__ __align__(16) char As[64 * 528];
  const int nb = blockIdx.x & 3, mb = blockIdx.x >> 2;   // mb 0..127
  const int tid = threadIdx.x;
  const int lane = tid & 63, w = tid >> 6, tl = lane & 15, q = lane >> 4;
  const int b = mb >> 6;
  const int nbase = (mb & 63) * 64;
  constexpr float invNK = 1.0f / 40960.0f;
  float4v acc[4];
#pragma unroll
  for (int t = 0; t < 4; ++t) acc[t] = (float4v){0.f, 0.f, 0.f, 0.f};
  const half8v* pf = (const half8v*)PF;
#pragma unroll 1
  for (int kc = 0; kc < 4; ++kc) {
    __syncthreads();
    for (int idx = tid; idx < 64 * 128; idx += 256) {
      int nl = idx >> 7, cp = idx & 127;
      size_t rowg = (size_t)(b << 12) + nbase + nl;
      __half2 v;
      if (kc == 0)      v = *(const __half2*)(featsT + rowg * 256 + cp * 2);
      else if (kc == 1) v = *(const __half2*)(f1T + rowg * 256 + cp * 2);
      else {
        int c0 = (kc == 2 ? 0 : 256) + cp * 2;
        float x0 = hmax2[rowg * 512 + c0];
        float x1 = hmax2[rowg * 512 + c0 + 1];
        int t0 = b * 512 + c0;
        float mu0 = N1[t0] * invNK;
        float var0 = N2[t0] * invNK - mu0 * mu0;
        float rs0 = __frsqrt_rn(var0 + 1e-5f);
        float mu1 = N1[t0 + 1] * invNK;
        float var1 = N2[t0 + 1] * invNK - mu1 * mu1;
        float rs1 = __frsqrt_rn(var1 + 1e-5f);
        float y0 = (x0 - mu0) * rs0; y0 = y0 > 0.f ? y0 : 0.2f * y0;
        float y1 = (x1 - mu1) * rs1; y1 = y1 > 0.f ? y1 : 0.2f * y1;
        v = __floats2half2_rn(y0, y1);
      }
      *(__half2*)(As + nl * 528 + cp * 4) = v;
    }
    __syncthreads();
#pragma unroll
    for (int ks = 0; ks < 8; ++ks) {
      int ksg = kc * 8 + ks;
      half8v a = *(const half8v*)(As + (w * 16 + tl) * 528 + ks * 64 + q * 16);
#pragma unroll
      for (int t = 0; t < 4; ++t) {
        half8v bf = pf[(size_t)(((nb * 4 + t) * 32 + ksg)) * 64 + lane];
        acc[t] = __builtin_amdgcn_mfma_f32_16x16x32_f16(a, bf, acc[t], 0, 0, 0);
      }
    }
  }
#pragma unroll
  for (int t = 0; t < 4; ++t) {
    int o = (nb * 4 + t) * 16 + tl;
    float s1 = 0.f, s2 = 0.f;
#pragma unroll
    for (int r = 0; r < 4; ++r) {
      float v = acc[t][r];
      int n = nbase + w * 16 + q * 4 + r;
      h3[((size_t)(b << 12) + n) * 256 + o] = v;
      s1 += v;
      s2 = fmaf(v, v, s2);
    }
    s1 += __shfl_xor(s1, 16); s1 += __shfl_xor(s1, 32);
    s2 += __shfl_xor(s2, 16); s2 += __shfl_xor(s2, 32);
    if (q == 0) {
      atomicAdd(&A1[b * 256 + o], s1);
      atomicAdd(&A2[b * 256 + o], s2);
    }
  }
}

// ---------------- final: transpose-norm h3 -> d_out, mu/rs inline ----------------
__global__ __launch_bounds__(256) void gcn_normT(const float* __restrict__ h3,
                                                 const float* __restrict__ A1,
                                                 const float* __restrict__ A2,
                                                 float* __restrict__ out) {
  __shared__ float tile[64][65];
  int x = blockIdx.x;
  int ob = x & 3, nb = (x >> 2) & 63, b = x >> 8;
  int n0 = nb * 64, o0 = ob * 64;
  for (int idx = threadIdx.x; idx < 4096; idx += 256) {
    int nl = idx >> 6, oc = idx & 63;
    tile[nl][oc] = h3[((size_t)(b << 12) + n0 + nl) * 256 + o0 + oc];
  }
  __syncthreads();
  constexpr float invN = 1.0f / 4096.0f;
  for (int idx = threadIdx.x; idx < 4096; idx += 256) {
    int ol = idx >> 6, nc = idx & 63;
    int t = b * 256 + o0 + ol;
    float mu = A1[t] * invN;
    float var = A2[t] * invN - mu * mu;
    float rs = __frsqrt_rn(var + 1e-5f);
    float v = (tile[nc][ol] - mu) * rs;
    v = v > 0.f ? v : 0.2f * v;
    out[((size_t)(b * 256 + o0 + ol) << 12) + n0 + nc] = v;
  }
}

// ---------------- launch ----------------
extern "C" void kernel_launch(void* const* d_in, const int* in_sizes, int n_in,
                              void* d_out, int out_size, void* d_ws, size_t ws_size,
                              hipStream_t stream) {
  (void)in_sizes; (void)n_in; (void)out_size; (void)ws_size;
  const float* coords  = (const float*)d_in[0];
  const float* feats   = (const float*)d_in[1];
  const float* W_lin1  = (const float*)d_in[2];
  const float* b_lin1  = (const float*)d_in[3];
  const float* W_lin2  = (const float*)d_in[4];
  const float* b_lin2  = (const float*)d_in[5];
  const float* W_conv1 = (const float*)d_in[6];
  const float* W_conv2 = (const float*)d_in[7];
  const float* W_conv3 = (const float*)d_in[8];
  char* ws = (char*)d_ws;

  float* A1_1    = (float*)(ws + OFF_A1_1);
  float* A2_1    = (float*)(ws + OFF_A2_1);
  float* A1_2    = (float*)(ws + OFF_A1_2);
  float* A2_2    = (float*)(ws + OFF_A2_2);
  float* A1_3    = (float*)(ws + OFF_A1_3);
  float* A2_3    = (float*)(ws + OFF_A2_3);
  float* F_MM    = (float*)(ws + OFF_MM);
  unsigned long long* KEYS = (unsigned long long*)(ws + OFF_KEYS);
  int* INDS      = (int*)(ws + OFF_INDS);
  _Float16* PK61 = (_Float16*)(ws + OFF_PK6_1);
  _Float16* PK62 = (_Float16*)(ws + OFF_PK6_2);
  _Float16* PK71 = (_Float16*)(ws + OFF_PK7_1);
  _Float16* PK72 = (_Float16*)(ws + OFF_PK7_2);
  float* WFOLD1  = (float*)(ws + OFF_WFOLD1);
  float* WFOLD2  = (float*)(ws + OFF_WFOLD2);
  _Float16* PC1  = (_Float16*)(ws + OFF_PC1);
  _Float16* PC2  = (_Float16*)(ws + OFF_PC2);
  float* BC1     = (float*)(ws + OFF_BC1);
  float* BC2     = (float*)(ws + OFF_BC2);
  __half* FEATST = (__half*)(ws + OFF_FEATST);
  __half* F1T    = (__half*)(ws + OFF_F1T);
  float* HMAX1   = (float*)(ws + OFF_HMAX1);
  float* HMAX2   = (float*)(ws + OFF_HMAX2);
  __half* HC1    = (__half*)(ws + OFF_HC1);
  __half* HC2    = (__half*)(ws + OFF_HC2);
  _Float16* PF3  = (_Float16*)(ws + OFF_PF3);
  float* H3      = (float*)(ws + OFF_H3);

  gcn_minmax<<<6, 256, 0, stream>>>(coords, F_MM);
  gcn_prep<<<PREP_BLOCKS, 1024, 0, stream>>>(
      coords, F_MM, KEYS, (float*)ws,
      feats, FEATST, W_lin1, W_lin2, W_conv1, W_conv2, W_conv3,
      WFOLD1, WFOLD2, PK61, PK62, PK71, PK72, PF3);
  gcn_stageB<<<768, 256, 0, stream>>>(W_conv1, b_lin1, W_conv2, b_lin2,
                                      WFOLD1, WFOLD2, PC1, BC1, PC2, BC2);
  // sort (8 blocks) overlaps hc<256> (128 blocks x 4 tiles)
  gcn_sort_hc<<<SORTHC_BLOCKS, 1024, 0, stream>>>(KEYS, INDS, FEATST, PC1, BC1, HC1);

  // layer 1 (perm1 = [2,0,3,1])
  gcn_window<256><<<1024, 1024, 0, stream>>>(
      FEATST, INDS, PK61, PK71, HC1,
      HMAX1, A1_1, A2_1, 2, 0, 3, 1);

  // fused: normalize(HMAX1) -> F1T + hc<512>
  gcn_norm_hc512<<<1024, 256, 0, stream>>>(HMAX1, A1_1, A2_1, F1T, PC2, BC2, HC2);

  // layer 2 (perm2 = [1,3,0,2])
  gcn_window<512><<<1024, 1024, 0, stream>>>(
      F1T, INDS, PK62, PK72, HC2,
      HMAX2, A1_2, A2_2, 1, 3, 0, 2);

  // final conv (MFMA, inline norm of HMAX2) + transpose-norm
  gcn_final_mfma<<<512, 256, 0, stream>>>(FEATST, F1T, HMAX2, A1_2, A2_2,
                                          PF3, H3, A1_3, A2_3);
  gcn_normT<<<512, 256, 0, stream>>>(H3, A1_3, A2_3, (float*)d_out);
}